// Round 7
// baseline (1959.458 us; speedup 1.0000x reference)
//
#include <hip/hip_runtime.h>
#include <math.h>

// MosfetFNO on MI355X — fused FNO layer v2: idft+skip+silu+store AND split-K
// forward-DFT of produced activations. MFMA bf16 hi/lo 3-product emulation.
// B=128, T=4096, Tp=4506, TPAD=4608 = 4 splits x 9 tiles x 128.
// ws (185,139,200 B exactly, same as round 3):
//   hx,lx u16 [128][64][4608]   2x75,497,472 B
//   xfp   f32 region 6291456 f32 reserved; [4][8192][128] used
//   coefh/l u16 [128][64][128]  2x2,097,152 B  (latb aliases coefh, lw2T
//                               aliases coefl; pw1T aliases coefh at the end)
//   fwdFh/l u16 [4608][128] ; invFh/l u16 [128][4608] ; skwh/l u16 [4][64][64]
#define B_     128
#define T_     4096
#define TP_    4506
#define TPAD_  4608
#define NSPL   4
#define NT_    9
#define NL_    4

typedef __attribute__((ext_vector_type(8))) short bf16x8;
typedef __attribute__((ext_vector_type(4))) float f32x4;
typedef unsigned short u16;

__device__ __forceinline__ float silu_f(float x){
  return x / (1.0f + expf(-x));
}
__device__ __forceinline__ float gelu_f(float x){
  float u = x + 0.044715f*x*x*x;
  return 0.5f*x*(1.0f + tanhf(0.7978845608028654f*u));
}
__device__ __forceinline__ u16 bf16_rne(float f){
  unsigned u = __float_as_uint(f);
  unsigned r = u + 0x7FFFu + ((u >> 16) & 1u);
  return (u16)(r >> 16);
}
__device__ __forceinline__ void bf16_split(float f, u16& h, u16& l){
  h = bf16_rne(f);
  float fh = __uint_as_float(((unsigned)h) << 16);
  l = bf16_rne(f - fh);
}
__device__ __forceinline__ void silu_split(float v, u16& h, u16& l){
  float s = v / (1.0f + __expf(-v));
  bf16_split(s, h, l);
}
__device__ __forceinline__ f32x4 mfma16(bf16x8 a, bf16x8 b, f32x4 c){
  return __builtin_amdgcn_mfma_f32_16x16x32_bf16(a, b, c, 0, 0, 0);
}

// ---------------------------------------------------------------- tables
__global__ __launch_bounds__(256) void k_tables(u16* __restrict__ fwdFh,
    u16* __restrict__ fwdFl, u16* __restrict__ invFh, u16* __restrict__ invFl){
  int idx = blockIdx.x*256 + threadIdx.x;
  if(idx >= TPAD_*64) return;
  int t = idx >> 6, m = idx & 63;
  float c = 0.f, s = 0.f;
  if(t < TP_){
    int r = (int)(((long long)m * (long long)t) % TP_);
    double ang = 6.283185307179586476925287 * (double)r / (double)TP_;
    c = (float)cos(ang);
    s = -(float)sin(ang);
  }
  u16 ch, cl, sh, sl;
  bf16_split(c, ch, cl);
  bf16_split(s, sh, sl);
  fwdFh[t*128 + m] = ch;      fwdFl[t*128 + m] = cl;
  fwdFh[t*128 + 64 + m] = sh; fwdFl[t*128 + 64 + m] = sl;
  invFh[(long)m*TPAD_ + t] = ch;      invFl[(long)m*TPAD_ + t] = cl;
  invFh[(long)(64+m)*TPAD_ + t] = sh; invFl[(long)(64+m)*TPAD_ + t] = sl;
}

// skw + lw2^T -> bf16 hi/lo
__global__ __launch_bounds__(256) void k_prep(const float* __restrict__ skw,
    u16* __restrict__ skwh, u16* __restrict__ skwl,
    const float* __restrict__ lw2, u16* __restrict__ lw2Th,
    u16* __restrict__ lw2Tl){
  int i = blockIdx.x*256 + threadIdx.x;
  if(i < NL_*64*64){
    u16 h, l; bf16_split(skw[i], h, l);
    skwh[i] = h; skwl[i] = l;
  } else if(i < NL_*64*64 + 64*128){
    int j = i - NL_*64*64;
    int w = j >> 7, d = j & 127;
    u16 h, l; bf16_split(lw2[d*64 + w], h, l);
    lw2Th[j] = h; lw2Tl[j] = l;
  }
}

// pw1^T -> bf16 hi/lo (runs after last fused layer; coef region dead)
__global__ __launch_bounds__(256) void k_prep2(const float* __restrict__ pw1,
    u16* __restrict__ pw1Th, u16* __restrict__ pw1Tl){
  int i = blockIdx.x*256 + threadIdx.x;
  if(i >= 64*128) return;
  int d = i >> 6, w = i & 63;
  u16 h, l; bf16_split(pw1[w*128 + d], h, l);
  pw1Th[i] = h; pw1Tl[i] = l;
}

// ---------------------------------------------------------------- embed
__global__ __launch_bounds__(128) void k_embed(
    const float* __restrict__ pp,
    const float* __restrict__ ew1, const float* __restrict__ eb1,
    const float* __restrict__ ew2, const float* __restrict__ eb2,
    const float* __restrict__ ew3, const float* __restrict__ eb3,
    const float* __restrict__ lw1, const float* __restrict__ lb1,
    float* __restrict__ latb)
{
  int b = blockIdx.x, tid = threadIdx.x;
  __shared__ float p[64], h1[128], h2[128], e[32];
  if(tid < 64) p[tid] = pp[b*64 + tid];
  __syncthreads();
  {
    float z = eb1[tid];
    for(int j=0;j<64;j++) z += p[j]*ew1[j*128 + tid];
    h1[tid] = gelu_f(z);
  }
  __syncthreads();
  {
    float z = eb2[tid];
    for(int j=0;j<128;j++) z += h1[j]*ew2[j*128 + tid];
    h2[tid] = gelu_f(z);
  }
  __syncthreads();
  if(tid < 32){
    float z = eb3[tid];
    for(int j=0;j<128;j++) z += h2[j]*ew3[j*32 + tid];
    e[tid] = tanhf(z);
  }
  __syncthreads();
  {
    float v = lb1[tid];
    for(int c=0;c<32;c++) v += e[c]*lw1[(4+c)*128 + tid];
    latb[b*128 + tid] = v;
  }
}

// ---------------------------------------------------------------- lift (MFMA)
__global__ __launch_bounds__(256) void k_lift(
    const float* __restrict__ vterm, const float* __restrict__ latb,
    const float* __restrict__ lw1,  const u16* __restrict__ lw2Th,
    const u16* __restrict__ lw2Tl, const float* __restrict__ lb2,
    u16* __restrict__ hx, u16* __restrict__ lx)
{
  int tt = blockIdx.x, b = blockIdx.y, tid = threadIdx.x;
  int t0 = tt*128;
  if(t0 >= T_){
    int r = tid >> 2, t00 = (tid & 3)*32;
    bf16x8 z8 = (bf16x8){0,0,0,0,0,0,0,0};
    long base = ((long)b*64 + r)*TPAD_ + t0 + t00;
    #pragma unroll
    for(int q=0;q<4;q++){
      *(bf16x8*)(hx + base + q*8) = z8;
      *(bf16x8*)(lx + base + q*8) = z8;
    }
    return;
  }
  __shared__ u16 zz[32768];
  u16* zh = zz;
  u16* zl = zz + 16384;
  __shared__ float vt[512], lw1c[512], latbs[128];
  if(tid < 128){
    int c = tid >> 5, tc = (tid & 31)*4;
    *(float4*)(vt + c*128 + tc) =
      *(const float4*)(vterm + ((long)b*4 + c)*T_ + t0 + tc);
  } else {
    int i = (tid - 128)*4;
    *(float4*)(lw1c + i) = *(const float4*)(lw1 + i);
  }
  if(tid < 32)
    *(float4*)(latbs + tid*4) = *(const float4*)(latb + b*128 + tid*4);
  __syncthreads();
  {
    int t = tid >> 1, dh = (tid & 1)*64;
    float v0 = vt[t], v1 = vt[128+t], v2 = vt[256+t], v3 = vt[384+t];
    int swz = (t & 7) << 4;
    #pragma unroll
    for(int q=0;q<16;q++){
      int d0 = dh + q*4;
      float4 w0 = *(const float4*)(lw1c + d0);
      float4 w1 = *(const float4*)(lw1c + 128 + d0);
      float4 w2 = *(const float4*)(lw1c + 256 + d0);
      float4 w3 = *(const float4*)(lw1c + 384 + d0);
      float4 lb = *(const float4*)(latbs + d0);
      u16 h0,h1,h2,h3,l0,l1,l2,l3;
      silu_split(lb.x + w0.x*v0 + w1.x*v1 + w2.x*v2 + w3.x*v3, h0, l0);
      silu_split(lb.y + w0.y*v0 + w1.y*v1 + w2.y*v2 + w3.y*v3, h1, l1);
      silu_split(lb.z + w0.z*v0 + w1.z*v1 + w2.z*v2 + w3.z*v3, h2, l2);
      silu_split(lb.w + w0.w*v0 + w1.w*v1 + w2.w*v2 + w3.w*v3, h3, l3);
      int byt = (t*256 + d0*2) ^ swz;
      uint2 hv = make_uint2((unsigned)h0 | ((unsigned)h1<<16),
                            (unsigned)h2 | ((unsigned)h3<<16));
      uint2 lv = make_uint2((unsigned)l0 | ((unsigned)l1<<16),
                            (unsigned)l2 | ((unsigned)l3<<16));
      *(uint2*)((char*)zh + byt) = hv;
      *(uint2*)((char*)zl + byt) = lv;
    }
  }
  __syncthreads();
  int lane = tid & 63, w = tid >> 6;
  int l15 = lane & 15, lhi = lane >> 4;
  int n0 = w*32;
  f32x4 acc[4][2];
  #pragma unroll
  for(int mi=0;mi<4;mi++){
    #pragma unroll
    for(int ni=0;ni<2;ni++) acc[mi][ni] = (f32x4){0.f,0.f,0.f,0.f};
  }
  #pragma unroll
  for(int ks=0; ks<4; ++ks){
    bf16x8 Ah[4], Al[4], Bh[2], Bl[2];
    #pragma unroll
    for(int mi=0;mi<4;mi++){
      int o = mi*16 + l15;
      long off = (long)o*128 + ks*32 + lhi*8;
      Ah[mi] = *(const bf16x8*)(lw2Th + off);
      Al[mi] = *(const bf16x8*)(lw2Tl + off);
    }
    #pragma unroll
    for(int ni=0;ni<2;ni++){
      int t = n0 + ni*16 + l15;
      int byt = (t*256 + (ks*32 + lhi*8)*2) ^ ((t & 7) << 4);
      Bh[ni] = *(bf16x8*)((char*)zh + byt);
      Bl[ni] = *(bf16x8*)((char*)zl + byt);
    }
    #pragma unroll
    for(int mi=0;mi<4;mi++){
      #pragma unroll
      for(int ni=0;ni<2;ni++){
        acc[mi][ni] = mfma16(Ah[mi], Bh[ni], acc[mi][ni]);
        acc[mi][ni] = mfma16(Al[mi], Bh[ni], acc[mi][ni]);
        acc[mi][ni] = mfma16(Ah[mi], Bl[ni], acc[mi][ni]);
      }
    }
  }
  __syncthreads();
  float* fo = (float*)zz;
  #pragma unroll
  for(int mi=0;mi<4;mi++){
    #pragma unroll
    for(int ni=0;ni<2;ni++){
      #pragma unroll
      for(int r=0;r<4;r++){
        int o = mi*16 + lhi*4 + r;
        int tl = n0 + ni*16 + l15;
        fo[o*128 + (tl ^ ((o&7)<<2))] = acc[mi][ni][r];
      }
    }
  }
  __syncthreads();
  #pragma unroll
  for(int q=0;q<8;q++){
    int idx = q*256 + tid;
    int o = idx >> 5, tb = idx & 31;
    float4 rd = *(const float4*)(fo + o*128 + ((tb*4) ^ ((o&7)<<2)));
    float bias = lb2[o];
    u16 h0,h1,h2,h3,l0,l1,l2,l3;
    silu_split(rd.x + bias, h0, l0);
    silu_split(rd.y + bias, h1, l1);
    silu_split(rd.z + bias, h2, l2);
    silu_split(rd.w + bias, h3, l3);
    long base = ((long)b*64 + o)*TPAD_ + t0 + tb*4;
    *(uint2*)(hx + base) = make_uint2((unsigned)h0 | ((unsigned)h1<<16),
                                      (unsigned)h2 | ((unsigned)h3<<16));
    *(uint2*)(lx + base) = make_uint2((unsigned)l0 | ((unsigned)l1<<16),
                                      (unsigned)l2 | ((unsigned)l3<<16));
  }
}

// ---------------------------------------------------------------- layer-0 forward DFT (4-split)
__global__ __launch_bounds__(256) void k_dft(
    const u16* __restrict__ hx, const u16* __restrict__ lx,
    const u16* __restrict__ invFh, const u16* __restrict__ invFl,
    float* __restrict__ xfp)
{
  int b = blockIdx.x, s = blockIdx.y, tid = threadIdx.x;
  int lane = tid & 63, w = tid >> 6;
  int l15 = lane & 15, lhi = lane >> 4;
  long k0 = (long)s*1152;
  const u16* rowAh = hx + ((long)b*64 + w*16 + l15)*TPAD_ + k0 + lhi*8;
  const u16* rowAl = lx + ((long)b*64 + w*16 + l15)*TPAD_ + k0 + lhi*8;
  const u16* rowBh = invFh + (long)l15*TPAD_ + k0 + lhi*8;
  const u16* rowBl = invFl + (long)l15*TPAD_ + k0 + lhi*8;
  f32x4 acc[8];
  #pragma unroll
  for(int ni=0;ni<8;ni++) acc[ni] = (f32x4){0.f,0.f,0.f,0.f};
  #pragma unroll 2
  for(int ks=0; ks<36; ++ks){
    bf16x8 Ah = *(const bf16x8*)(rowAh + ks*32);
    bf16x8 Al = *(const bf16x8*)(rowAl + ks*32);
    #pragma unroll
    for(int ni=0;ni<8;ni++){
      bf16x8 Bh = *(const bf16x8*)(rowBh + (long)ni*16*TPAD_ + ks*32);
      bf16x8 Bl = *(const bf16x8*)(rowBl + (long)ni*16*TPAD_ + ks*32);
      acc[ni] = mfma16(Ah, Bh, acc[ni]);
      acc[ni] = mfma16(Al, Bh, acc[ni]);
      acc[ni] = mfma16(Ah, Bl, acc[ni]);
    }
  }
  #pragma unroll
  for(int ni=0;ni<8;ni++){
    #pragma unroll
    for(int r=0;r<4;r++){
      int row = w*16 + lhi*4 + r;
      xfp[((long)s*8192 + b*64 + row)*128 + ni*16 + l15] = acc[ni][r];
    }
  }
}

// ---------------------------------------------------------------- spectral mix (4 splits)
__global__ __launch_bounds__(512) void k_spectral(
    const float* __restrict__ xfp, const float* __restrict__ wr_,
    const float* __restrict__ wi_, u16* __restrict__ coefh,
    u16* __restrict__ coefl, int l)
{
  int b = blockIdx.x, mh = blockIdx.y, tid = threadIdx.x;
  const float* wr = wr_ + (long)l*262144;
  const float* wi = wi_ + (long)l*262144;
  __shared__ float xr[64*36], xi[64*36];
  {
    int c = tid >> 3, mm0 = (tid & 7)*4;
    long base = ((long)(b*64 + c))*128 + mh*32 + mm0;
    float4 sr = make_float4(0.f,0.f,0.f,0.f), si = sr;
    #pragma unroll
    for(int s2=0;s2<NSPL;s2++){
      const float* p = xfp + (long)s2*1048576 + base;
      float4 a = *(const float4*)(p);
      float4 d = *(const float4*)(p + 64);
      sr.x += a.x; sr.y += a.y; sr.z += a.z; sr.w += a.w;
      si.x += d.x; si.y += d.y; si.z += d.z; si.w += d.w;
    }
    *(float4*)(xr + c*36 + mm0) = sr;
    *(float4*)(xi + c*36 + mm0) = si;
  }
  __syncthreads();
  int tx = tid & 15, ty = tid >> 4;
  float ar[2][2] = {{0.f,0.f},{0.f,0.f}};
  float ai[2][2] = {{0.f,0.f},{0.f,0.f}};
  #pragma unroll 2
  for(int c=0;c<64;c++){
    float x0r = xr[c*36 + 2*tx], x1r = xr[c*36 + 2*tx + 1];
    float x0i = xi[c*36 + 2*tx], x1i = xi[c*36 + 2*tx + 1];
    #pragma unroll
    for(int oi=0;oi<2;oi++){
      int o = 2*ty + oi;
      long wofs = ((long)(c*64 + o))*64 + mh*32 + 2*tx;
      float2 wrv = *(const float2*)(wr + wofs);
      float2 wiv = *(const float2*)(wi + wofs);
      ar[oi][0] += x0r*wrv.x - x0i*wiv.x;
      ai[oi][0] += x0r*wiv.x + x0i*wrv.x;
      ar[oi][1] += x1r*wrv.y - x1i*wiv.y;
      ai[oi][1] += x1r*wiv.y + x1i*wrv.y;
    }
  }
  #pragma unroll
  for(int j=0;j<2;j++){
    int m = mh*32 + 2*tx + j;
    float sc = (m==0) ? (1.0f/(float)TP_) : (2.0f/(float)TP_);
    #pragma unroll
    for(int oi=0;oi<2;oi++){
      int o = 2*ty + oi;
      long base = ((long)b*64 + o)*128;
      u16 h, l2;
      bf16_split(sc*ar[oi][j], h, l2);
      coefh[base + m] = h; coefl[base + m] = l2;
      bf16_split(sc*ai[oi][j], h, l2);
      coefh[base + 64 + m] = h; coefl[base + 64 + m] = l2;
    }
  }
}

// ---------------------------------------------------------------- fused layer v2
// grid (NSPL, B): block owns t in [s*1152, s*1152+1152) = 9 tiles of 128.
// Per tile: stage input h ([t][c], transposed); accV = idft(coef) + skip(h);
// h' = silu(accV+bias) (raw if last); store h' global + keep in LDS [c][t];
// DFT previous tile's h' into accF; accF -> xfp[s] at the end.
__global__ __launch_bounds__(512) void k_fused(
    u16* __restrict__ hx, u16* __restrict__ lx,
    const u16* __restrict__ coefh, const u16* __restrict__ coefl,
    const u16* __restrict__ fwdFh, const u16* __restrict__ fwdFl,
    const u16* __restrict__ skwh, const u16* __restrict__ skwl,
    const u16* __restrict__ invFh, const u16* __restrict__ invFl,
    const float* __restrict__ sb_, float* __restrict__ xfp,
    int lay, int last)
{
  int s = blockIdx.x, b = blockIdx.y, tid = threadIdx.x;
  int lane = tid & 63, w = tid >> 6;
  int l15 = lane & 15, lhi = lane >> 4;
  int tbase = s*1152;
  int jn = w*16 + l15;
  __shared__ u16 P0[16384];
  __shared__ u16 P1[16384];
  // staging map (input -> [t][c], 2 c-rows x 8 t per thread)
  int c0 = (tid & 31)*2, tg = tid >> 5;
  long rowg = ((long)b*64 + c0)*TPAD_ + tbase + tg*8;
  // output map ([c][t] LDS write + coalesced global store)
  int oc = tid >> 3, seg = tid & 7;
  long outg = ((long)b*64 + oc)*TPAD_ + tbase + seg*16;
  int obase = oc*256 + seg*32, oswz = (oc & 7) << 4;

  f32x4 accF[4];
  #pragma unroll
  for(int mi=0;mi<4;mi++) accF[mi] = (f32x4){0.f,0.f,0.f,0.f};

  uint4 ph0 = *(const uint4*)(hx + rowg);
  uint4 ph1 = *(const uint4*)(hx + rowg + TPAD_);
  uint4 pl0 = *(const uint4*)(lx + rowg);
  uint4 pl1 = *(const uint4*)(lx + rowg + TPAD_);

  for(int tt=0; tt<NT_; ++tt){
    u16* inH = (tt & 1) ? P1 : P0;        // input h, [t][c]
    u16* hoH = (tt & 1) ? P0 : P1;        // h'(tt-1) [c][t] at entry; fo later
    u16* inL = inH + 8192;
    u16* hoL = hoH + 8192;
    int t0g = tbase + tt*128;
    { // phase 1: scatter prefetched tile into [t][c]
      const u16* a0 = (const u16*)&ph0;
      const u16* a1 = (const u16*)&ph1;
      const u16* d0 = (const u16*)&pl0;
      const u16* d1 = (const u16*)&pl1;
      #pragma unroll
      for(int i=0;i<8;i++){
        int t = tg*8 + i;
        int byt = (t*128 + c0*2) ^ ((t & 7) << 4);
        *(unsigned*)((char*)inH + byt) =
          (unsigned)a0[i] | ((unsigned)a1[i] << 16);
        *(unsigned*)((char*)inL + byt) =
          (unsigned)d0[i] | ((unsigned)d1[i] << 16);
      }
    }
    if(tt + 1 < NT_){ // phase 2: prefetch next tile
      long g = rowg + (long)(tt+1)*128;
      ph0 = *(const uint4*)(hx + g);
      ph1 = *(const uint4*)(hx + g + TPAD_);
      pl0 = *(const uint4*)(lx + g);
      pl1 = *(const uint4*)(lx + g + TPAD_);
    }
    __syncthreads();
    // phase 4: MFMAs
    f32x4 accV[4];
    #pragma unroll
    for(int mi=0;mi<4;mi++) accV[mi] = (f32x4){0.f,0.f,0.f,0.f};
    #pragma unroll
    for(int ks=0; ks<4; ++ks){            // spectral idft, K=128
      bf16x8 Ah[4], Al[4], Bh, Bl;
      #pragma unroll
      for(int mi=0;mi<4;mi++){
        long off = ((long)(b*64 + mi*16 + l15))*128 + ks*32 + lhi*8;
        Ah[mi] = *(const bf16x8*)(coefh + off);
        Al[mi] = *(const bf16x8*)(coefl + off);
      }
      { long off = (long)(t0g + jn)*128 + ks*32 + lhi*8;
        Bh = *(const bf16x8*)(fwdFh + off);
        Bl = *(const bf16x8*)(fwdFl + off); }
      #pragma unroll
      for(int mi=0;mi<4;mi++){
        accV[mi] = mfma16(Ah[mi], Bh, accV[mi]);
        accV[mi] = mfma16(Al[mi], Bh, accV[mi]);
        accV[mi] = mfma16(Ah[mi], Bl, accV[mi]);
      }
    }
    #pragma unroll
    for(int ks=0; ks<2; ++ks){            // skip, K=64, B from inH [t][c]
      bf16x8 Ah[4], Al[4], Bh, Bl;
      #pragma unroll
      for(int mi=0;mi<4;mi++){
        long off = (long)lay*4096 + (mi*16 + l15)*64 + ks*32 + lhi*8;
        Ah[mi] = *(const bf16x8*)(skwh + off);
        Al[mi] = *(const bf16x8*)(skwl + off);
      }
      { int byt = (jn*128 + (ks*32 + lhi*8)*2) ^ ((jn & 7) << 4);
        Bh = *(bf16x8*)((char*)inH + byt);
        Bl = *(bf16x8*)((char*)inL + byt); }
      #pragma unroll
      for(int mi=0;mi<4;mi++){
        accV[mi] = mfma16(Ah[mi], Bh, accV[mi]);
        accV[mi] = mfma16(Al[mi], Bh, accV[mi]);
        accV[mi] = mfma16(Ah[mi], Bl, accV[mi]);
      }
    }
    if(tt > 0 && !last){                  // DFT of h'(tt-1), A from hoH [c][t]
      #pragma unroll
      for(int ks=0; ks<4; ++ks){
        bf16x8 Ah[4], Al[4], Bh, Bl;
        #pragma unroll
        for(int mi=0;mi<4;mi++){
          int c = mi*16 + l15;
          int byt = (c*256 + (ks*32 + lhi*8)*2) ^ ((c & 7) << 4);
          Ah[mi] = *(bf16x8*)((char*)hoH + byt);
          Al[mi] = *(bf16x8*)((char*)hoL + byt);
        }
        { long off = (long)jn*TPAD_ + (t0g - 128) + ks*32 + lhi*8;
          Bh = *(const bf16x8*)(invFh + off);
          Bl = *(const bf16x8*)(invFl + off); }
        #pragma unroll
        for(int mi=0;mi<4;mi++){
          accF[mi] = mfma16(Ah[mi], Bh, accF[mi]);
          accF[mi] = mfma16(Al[mi], Bh, accF[mi]);
          accF[mi] = mfma16(Ah[mi], Bl, accF[mi]);
        }
      }
    }
    __syncthreads();
    { // phase 6: accV + bias -> fo (f32, swizzled) in dead hoH/hoL space
      float* fo = (float*)hoH;
      #pragma unroll
      for(int mi=0;mi<4;mi++){
        #pragma unroll
        for(int r=0;r<4;r++){
          int o = mi*16 + lhi*4 + r;
          fo[o*128 + (jn ^ ((o&7)<<2))] = accV[mi][r] + sb_[lay*64 + o];
        }
      }
    }
    __syncthreads();
    { // phase 8: fo -> zero/silu/split -> global store + LDS [c][t] (inH)
      float* fo = (float*)hoH;
      uint2 hp[4], lp[4];
      #pragma unroll
      for(int q=0;q<4;q++){
        int tloc = seg*16 + q*4;
        float4 rd = *(const float4*)(fo + oc*128 + (tloc ^ ((oc&7)<<2)));
        float v[4] = {rd.x, rd.y, rd.z, rd.w};
        #pragma unroll
        for(int j2=0;j2<4;j2++){
          int tg2 = t0g + tloc + j2;
          if(tg2 >= TP_) v[j2] = 0.f;
          else if(!last) v[j2] = silu_f(v[j2]);
        }
        u16 h0,h1,h2,h3,l0,l1,l2,l3;
        bf16_split(v[0], h0, l0);
        bf16_split(v[1], h1, l1);
        bf16_split(v[2], h2, l2);
        bf16_split(v[3], h3, l3);
        hp[q] = make_uint2((unsigned)h0 | ((unsigned)h1<<16),
                           (unsigned)h2 | ((unsigned)h3<<16));
        lp[q] = make_uint2((unsigned)l0 | ((unsigned)l1<<16),
                           (unsigned)l2 | ((unsigned)l3<<16));
      }
      uint4 H0 = make_uint4(hp[0].x, hp[0].y, hp[1].x, hp[1].y);
      uint4 H1 = make_uint4(hp[2].x, hp[2].y, hp[3].x, hp[3].y);
      uint4 L0 = make_uint4(lp[0].x, lp[0].y, lp[1].x, lp[1].y);
      uint4 L1 = make_uint4(lp[2].x, lp[2].y, lp[3].x, lp[3].y);
      long g = outg + (long)tt*128;
      *(uint4*)(hx + g)     = H0;
      *(uint4*)(hx + g + 8) = H1;
      *(uint4*)(lx + g)     = L0;
      *(uint4*)(lx + g + 8) = L1;
      if(!last){
        *(uint4*)((char*)inH + ((obase)      ^ oswz)) = H0;
        *(uint4*)((char*)inH + ((obase + 16) ^ oswz)) = H1;
        *(uint4*)((char*)inL + ((obase)      ^ oswz)) = L0;
        *(uint4*)((char*)inL + ((obase + 16) ^ oswz)) = L1;
      }
    }
    __syncthreads();
  }
  if(!last){
    // DFT of last tile's h' (in P0, since (NT_-1)&1 == 0)
    u16* hoH = P0;
    u16* hoL = P0 + 8192;
    #pragma unroll
    for(int ks=0; ks<4; ++ks){
      bf16x8 Ah[4], Al[4], Bh, Bl;
      #pragma unroll
      for(int mi=0;mi<4;mi++){
        int c = mi*16 + l15;
        int byt = (c*256 + (ks*32 + lhi*8)*2) ^ ((c & 7) << 4);
        Ah[mi] = *(bf16x8*)((char*)hoH + byt);
        Al[mi] = *(bf16x8*)((char*)hoL + byt);
      }
      { long off = (long)jn*TPAD_ + (tbase + (NT_-1)*128) + ks*32 + lhi*8;
        Bh = *(const bf16x8*)(invFh + off);
        Bl = *(const bf16x8*)(invFl + off); }
      #pragma unroll
      for(int mi=0;mi<4;mi++){
        accF[mi] = mfma16(Ah[mi], Bh, accF[mi]);
        accF[mi] = mfma16(Al[mi], Bh, accF[mi]);
        accF[mi] = mfma16(Ah[mi], Bl, accF[mi]);
      }
    }
    #pragma unroll
    for(int mi=0;mi<4;mi++){
      #pragma unroll
      for(int r=0;r<4;r++){
        int c = mi*16 + lhi*4 + r;
        xfp[(long)s*1048576 + ((long)(b*64 + c))*128 + jn] = accF[mi][r];
      }
    }
  }
}

// ---------------------------------------------------------------- projection (MFMA)
__global__ __launch_bounds__(256) void k_proj(
    const u16* __restrict__ hx, const u16* __restrict__ lx,
    const u16* __restrict__ pw1Th, const u16* __restrict__ pw1Tl,
    const float* __restrict__ pb1, const float* __restrict__ pw2,
    const float* __restrict__ pb2, float* __restrict__ out)
{
  int tt = blockIdx.x, b = blockIdx.y, tid = threadIdx.x;
  int t0 = tt*128;
  int lane = tid & 63, w = tid >> 6;
  int l15 = lane & 15, lhi = lane >> 4;
  __shared__ u16 sh_[16384];           // x tile transposed [128t][64c] h/l
  u16* hh = sh_;
  u16* hl = sh_ + 8192;
  {
    int c0 = (tid & 31)*2, tg = tid >> 5;
    const u16* ph0 = hx + ((long)b*64 + c0)*TPAD_ + t0 + tg*16;
    const u16* ph1 = ph0 + TPAD_;
    const u16* pl0 = lx + ((long)b*64 + c0)*TPAD_ + t0 + tg*16;
    const u16* pl1 = pl0 + TPAD_;
    bf16x8 h0a = *(const bf16x8*)(ph0),     h0b = *(const bf16x8*)(ph0 + 8);
    bf16x8 h1a = *(const bf16x8*)(ph1),     h1b = *(const bf16x8*)(ph1 + 8);
    bf16x8 l0a = *(const bf16x8*)(pl0),     l0b = *(const bf16x8*)(pl0 + 8);
    bf16x8 l1a = *(const bf16x8*)(pl1),     l1b = *(const bf16x8*)(pl1 + 8);
    #pragma unroll
    for(int i=0;i<8;i++){
      int t = tg*16 + i;
      int byt = (t*128 + c0*2) ^ ((t & 7) << 4);
      *(unsigned*)((char*)hh + byt) =
        (unsigned)(u16)h0a[i] | ((unsigned)(u16)h1a[i] << 16);
      *(unsigned*)((char*)hl + byt) =
        (unsigned)(u16)l0a[i] | ((unsigned)(u16)l1a[i] << 16);
    }
    #pragma unroll
    for(int i=0;i<8;i++){
      int t = tg*16 + 8 + i;
      int byt = (t*128 + c0*2) ^ ((t & 7) << 4);
      *(unsigned*)((char*)hh + byt) =
        (unsigned)(u16)h0b[i] | ((unsigned)(u16)h1b[i] << 16);
      *(unsigned*)((char*)hl + byt) =
        (unsigned)(u16)l0b[i] | ((unsigned)(u16)l1b[i] << 16);
    }
  }
  __syncthreads();
  f32x4 acc[2][8];
  #pragma unroll
  for(int mi=0;mi<2;mi++){
    #pragma unroll
    for(int ni=0;ni<8;ni++) acc[mi][ni] = (f32x4){0.f,0.f,0.f,0.f};
  }
  #pragma unroll
  for(int ks=0; ks<2; ++ks){
    bf16x8 Ah[2], Al[2], Bh[8], Bl[8];
    #pragma unroll
    for(int mi=0;mi<2;mi++){
      int t = w*32 + mi*16 + l15;
      int byt = (t*128 + (ks*32 + lhi*8)*2) ^ ((t & 7) << 4);
      Ah[mi] = *(bf16x8*)((char*)hh + byt);
      Al[mi] = *(bf16x8*)((char*)hl + byt);
    }
    #pragma unroll
    for(int ni=0;ni<8;ni++){
      long off = (long)(ni*16 + l15)*64 + ks*32 + lhi*8;
      Bh[ni] = *(const bf16x8*)(pw1Th + off);
      Bl[ni] = *(const bf16x8*)(pw1Tl + off);
    }
    #pragma unroll
    for(int mi=0;mi<2;mi++){
      #pragma unroll
      for(int ni=0;ni<8;ni++){
        acc[mi][ni] = mfma16(Ah[mi], Bh[ni], acc[mi][ni]);
        acc[mi][ni] = mfma16(Al[mi], Bh[ni], acc[mi][ni]);
        acc[mi][ni] = mfma16(Ah[mi], Bl[ni], acc[mi][ni]);
      }
    }
  }
  #pragma unroll
  for(int mi=0;mi<2;mi++){
    #pragma unroll
    for(int r=0;r<4;r++){
      int t = w*32 + mi*16 + lhi*4 + r;
      float s = 0.f;
      #pragma unroll
      for(int ni=0;ni<8;ni++){
        int d = ni*16 + l15;
        s += pw2[d] * silu_f(acc[mi][ni][r] + pb1[d]);
      }
      s += __shfl_xor(s, 1);
      s += __shfl_xor(s, 2);
      s += __shfl_xor(s, 4);
      s += __shfl_xor(s, 8);
      if(l15 == 0) out[(long)b*T_ + t0 + t] = s + pb2[0];
    }
  }
}

// ---------------------------------------------------------------- launch
extern "C" void kernel_launch(void* const* d_in, const int* in_sizes, int n_in,
                              void* d_out, int out_size, void* d_ws, size_t ws_size,
                              hipStream_t stream)
{
  const float* vterm = (const float*)d_in[0];
  const float* pp    = (const float*)d_in[1];
  const float* ew1   = (const float*)d_in[2];
  const float* eb1   = (const float*)d_in[3];
  const float* ew2   = (const float*)d_in[4];
  const float* eb2   = (const float*)d_in[5];
  const float* ew3   = (const float*)d_in[6];
  const float* eb3   = (const float*)d_in[7];
  const float* lw1   = (const float*)d_in[8];
  const float* lb1   = (const float*)d_in[9];
  const float* lw2   = (const float*)d_in[10];
  const float* lb2   = (const float*)d_in[11];
  const float* swr   = (const float*)d_in[12];
  const float* swi   = (const float*)d_in[13];
  const float* skw   = (const float*)d_in[14];
  const float* skb   = (const float*)d_in[15];
  const float* pw1   = (const float*)d_in[16];
  const float* pb1   = (const float*)d_in[17];
  const float* pw2   = (const float*)d_in[18];
  const float* pb2   = (const float*)d_in[19];
  float* out = (float*)d_out;

  u16* hx     = (u16*)d_ws;
  u16* lxp    = hx + 37748736;
  float* xfp  = (float*)(lxp + 37748736);
  u16* coefh  = (u16*)(xfp + 6291456);
  u16* coefl  = coefh + 1048576;
  u16* fwdFh  = coefl + 1048576;
  u16* fwdFl  = fwdFh + 589824;
  u16* invFh  = fwdFl + 589824;
  u16* invFl  = invFh + 589824;
  u16* skwh   = invFl + 589824;
  u16* skwl   = skwh + 16384;
  float* latb = (float*)coefh;   // dead before spectral writes coef
  u16* lw2Th  = coefl;           // dead before spectral writes coef
  u16* lw2Tl  = coefl + 8192;
  u16* pw1Th  = coefh;           // written by k_prep2 after coef is dead
  u16* pw1Tl  = coefh + 8192;

  k_tables<<<(TPAD_*64 + 255)/256, 256, 0, stream>>>(fwdFh, fwdFl, invFh, invFl);
  k_prep<<<(NL_*64*64 + 64*128 + 255)/256, 256, 0, stream>>>(
      skw, skwh, skwl, lw2, lw2Th, lw2Tl);
  k_embed<<<B_, 128, 0, stream>>>(pp, ew1, eb1, ew2, eb2, ew3, eb3, lw1, lb1, latb);
  k_lift<<<dim3(TPAD_/128, B_), 256, 0, stream>>>(
      vterm, latb, lw1, lw2Th, lw2Tl, lb2, hx, lxp);
  k_dft<<<dim3(B_, NSPL), 256, 0, stream>>>(hx, lxp, invFh, invFl, xfp);
  for(int l=0;l<NL_;l++){
    k_spectral<<<dim3(B_, 2), 512, 0, stream>>>(xfp, swr, swi, coefh, coefl, l);
    k_fused<<<dim3(NSPL, B_), 512, 0, stream>>>(
        hx, lxp, coefh, coefl, fwdFh, fwdFl, skwh, skwl, invFh, invFl,
        skb, xfp, l, (l==NL_-1) ? 1 : 0);
  }
  k_prep2<<<32, 256, 0, stream>>>(pw1, pw1Th, pw1Tl);
  k_proj<<<dim3(T_/128, B_), 256, 0, stream>>>(
      hx, lxp, pw1Th, pw1Tl, pb1, pw2, pb2, out);
}

// Round 8
// 1521.801 us; speedup vs baseline: 1.2876x; 1.2876x over previous
//
#include <hip/hip_runtime.h>
#include <math.h>

// MosfetFNO on MI355X — consolidated best-measured kernels.
// Pre-split silu'd activations hx/lx; LDS-staged split-K DFT with XCD swizzle;
// R4 idft (+nontemporal streaming); MFMA lift/proj. bf16 hi/lo 3-product emu.
// B=128, T=4096, Tp=4506, TPAD=4608 = 6 splits x 768.
// ws (185,139,200 B):
//   hx,lx u16 [128][64][4608]   2x75,497,472 B
//   xfp   f32 [6][8192][128]      25,165,824 B
//   coefh/l u16 [128][64][128]  2x2,097,152 B  (latb aliases coefh, lw2T
//                               aliases coefl; pw1T aliases coefh at the end)
//   fwdFh/l u16 [4608][128] ; invFh/l u16 [128][4608] ; skwh/l u16 [4][64][64]
#define B_     128
#define T_     4096
#define TP_    4506
#define TPAD_  4608
#define KSPLIT 6
#define NL_    4

typedef __attribute__((ext_vector_type(8))) short bf16x8;
typedef __attribute__((ext_vector_type(4))) float f32x4;
typedef unsigned short u16;
typedef unsigned long long u64;

__device__ __forceinline__ float silu_f(float x){
  return x / (1.0f + expf(-x));
}
__device__ __forceinline__ float gelu_f(float x){
  float u = x + 0.044715f*x*x*x;
  return 0.5f*x*(1.0f + tanhf(0.7978845608028654f*u));
}
__device__ __forceinline__ u16 bf16_rne(float f){
  unsigned u = __float_as_uint(f);
  unsigned r = u + 0x7FFFu + ((u >> 16) & 1u);
  return (u16)(r >> 16);
}
__device__ __forceinline__ void bf16_split(float f, u16& h, u16& l){
  h = bf16_rne(f);
  float fh = __uint_as_float(((unsigned)h) << 16);
  l = bf16_rne(f - fh);
}
__device__ __forceinline__ void silu_split(float v, u16& h, u16& l){
  float s = v / (1.0f + __expf(-v));
  bf16_split(s, h, l);
}
__device__ __forceinline__ f32x4 mfma16(bf16x8 a, bf16x8 b, f32x4 c){
  return __builtin_amdgcn_mfma_f32_16x16x32_bf16(a, b, c, 0, 0, 0);
}

// ---------------------------------------------------------------- tables
__global__ __launch_bounds__(256) void k_tables(u16* __restrict__ fwdFh,
    u16* __restrict__ fwdFl, u16* __restrict__ invFh, u16* __restrict__ invFl){
  int idx = blockIdx.x*256 + threadIdx.x;
  if(idx >= TPAD_*64) return;
  int t = idx >> 6, m = idx & 63;
  float c = 0.f, s = 0.f;
  if(t < TP_){
    int r = (int)(((long long)m * (long long)t) % TP_);
    double ang = 6.283185307179586476925287 * (double)r / (double)TP_;
    c = (float)cos(ang);
    s = -(float)sin(ang);
  }
  u16 ch, cl, sh, sl;
  bf16_split(c, ch, cl);
  bf16_split(s, sh, sl);
  fwdFh[t*128 + m] = ch;      fwdFl[t*128 + m] = cl;
  fwdFh[t*128 + 64 + m] = sh; fwdFl[t*128 + 64 + m] = sl;
  invFh[(long)m*TPAD_ + t] = ch;      invFl[(long)m*TPAD_ + t] = cl;
  invFh[(long)(64+m)*TPAD_ + t] = sh; invFl[(long)(64+m)*TPAD_ + t] = sl;
}

// skw + lw2^T -> bf16 hi/lo
__global__ __launch_bounds__(256) void k_prep(const float* __restrict__ skw,
    u16* __restrict__ skwh, u16* __restrict__ skwl,
    const float* __restrict__ lw2, u16* __restrict__ lw2Th,
    u16* __restrict__ lw2Tl){
  int i = blockIdx.x*256 + threadIdx.x;
  if(i < NL_*64*64){
    u16 h, l; bf16_split(skw[i], h, l);
    skwh[i] = h; skwl[i] = l;
  } else if(i < NL_*64*64 + 64*128){
    int j = i - NL_*64*64;
    int w = j >> 7, d = j & 127;
    u16 h, l; bf16_split(lw2[d*64 + w], h, l);
    lw2Th[j] = h; lw2Tl[j] = l;
  }
}

// pw1^T -> bf16 hi/lo (after last layer; coef region dead)
__global__ __launch_bounds__(256) void k_prep2(const float* __restrict__ pw1,
    u16* __restrict__ pw1Th, u16* __restrict__ pw1Tl){
  int i = blockIdx.x*256 + threadIdx.x;
  if(i >= 64*128) return;
  int d = i >> 6, w = i & 63;
  u16 h, l; bf16_split(pw1[w*128 + d], h, l);
  pw1Th[i] = h; pw1Tl[i] = l;
}

// ---------------------------------------------------------------- embed
__global__ __launch_bounds__(128) void k_embed(
    const float* __restrict__ pp,
    const float* __restrict__ ew1, const float* __restrict__ eb1,
    const float* __restrict__ ew2, const float* __restrict__ eb2,
    const float* __restrict__ ew3, const float* __restrict__ eb3,
    const float* __restrict__ lw1, const float* __restrict__ lb1,
    float* __restrict__ latb)
{
  int b = blockIdx.x, tid = threadIdx.x;
  __shared__ float p[64], h1[128], h2[128], e[32];
  if(tid < 64) p[tid] = pp[b*64 + tid];
  __syncthreads();
  {
    float z = eb1[tid];
    for(int j=0;j<64;j++) z += p[j]*ew1[j*128 + tid];
    h1[tid] = gelu_f(z);
  }
  __syncthreads();
  {
    float z = eb2[tid];
    for(int j=0;j<128;j++) z += h1[j]*ew2[j*128 + tid];
    h2[tid] = gelu_f(z);
  }
  __syncthreads();
  if(tid < 32){
    float z = eb3[tid];
    for(int j=0;j<128;j++) z += h2[j]*ew3[j*32 + tid];
    e[tid] = tanhf(z);
  }
  __syncthreads();
  {
    float v = lb1[tid];
    for(int c=0;c<32;c++) v += e[c]*lw1[(4+c)*128 + tid];
    latb[b*128 + tid] = v;
  }
}

// ---------------------------------------------------------------- lift (MFMA, R4 exact)
__global__ __launch_bounds__(256) void k_lift(
    const float* __restrict__ vterm, const float* __restrict__ latb,
    const float* __restrict__ lw1,  const u16* __restrict__ lw2Th,
    const u16* __restrict__ lw2Tl, const float* __restrict__ lb2,
    u16* __restrict__ hx, u16* __restrict__ lx)
{
  int tt = blockIdx.x, b = blockIdx.y, tid = threadIdx.x;
  int t0 = tt*128;
  if(t0 >= T_){
    int r = tid >> 2, t00 = (tid & 3)*32;
    bf16x8 z8 = (bf16x8){0,0,0,0,0,0,0,0};
    long base = ((long)b*64 + r)*TPAD_ + t0 + t00;
    #pragma unroll
    for(int q=0;q<4;q++){
      *(bf16x8*)(hx + base + q*8) = z8;
      *(bf16x8*)(lx + base + q*8) = z8;
    }
    return;
  }
  __shared__ u16 zz[32768];
  u16* zh = zz;
  u16* zl = zz + 16384;
  __shared__ float vt[512], lw1c[512], latbs[128];
  if(tid < 128){
    int c = tid >> 5, tc = (tid & 31)*4;
    *(float4*)(vt + c*128 + tc) =
      *(const float4*)(vterm + ((long)b*4 + c)*T_ + t0 + tc);
  } else {
    int i = (tid - 128)*4;
    *(float4*)(lw1c + i) = *(const float4*)(lw1 + i);
  }
  if(tid < 32)
    *(float4*)(latbs + tid*4) = *(const float4*)(latb + b*128 + tid*4);
  __syncthreads();
  {
    int t = tid >> 1, dh = (tid & 1)*64;
    float v0 = vt[t], v1 = vt[128+t], v2 = vt[256+t], v3 = vt[384+t];
    int swz = (t & 7) << 4;
    #pragma unroll
    for(int q=0;q<16;q++){
      int d0 = dh + q*4;
      float4 w0 = *(const float4*)(lw1c + d0);
      float4 w1 = *(const float4*)(lw1c + 128 + d0);
      float4 w2 = *(const float4*)(lw1c + 256 + d0);
      float4 w3 = *(const float4*)(lw1c + 384 + d0);
      float4 lb = *(const float4*)(latbs + d0);
      u16 h0,h1,h2,h3,l0,l1,l2,l3;
      silu_split(lb.x + w0.x*v0 + w1.x*v1 + w2.x*v2 + w3.x*v3, h0, l0);
      silu_split(lb.y + w0.y*v0 + w1.y*v1 + w2.y*v2 + w3.y*v3, h1, l1);
      silu_split(lb.z + w0.z*v0 + w1.z*v1 + w2.z*v2 + w3.z*v3, h2, l2);
      silu_split(lb.w + w0.w*v0 + w1.w*v1 + w2.w*v2 + w3.w*v3, h3, l3);
      int byt = (t*256 + d0*2) ^ swz;
      uint2 hv = make_uint2((unsigned)h0 | ((unsigned)h1<<16),
                            (unsigned)h2 | ((unsigned)h3<<16));
      uint2 lv = make_uint2((unsigned)l0 | ((unsigned)l1<<16),
                            (unsigned)l2 | ((unsigned)l3<<16));
      *(uint2*)((char*)zh + byt) = hv;
      *(uint2*)((char*)zl + byt) = lv;
    }
  }
  __syncthreads();
  int lane = tid & 63, w = tid >> 6;
  int l15 = lane & 15, lhi = lane >> 4;
  int n0 = w*32;
  f32x4 acc[4][2];
  #pragma unroll
  for(int mi=0;mi<4;mi++){
    #pragma unroll
    for(int ni=0;ni<2;ni++) acc[mi][ni] = (f32x4){0.f,0.f,0.f,0.f};
  }
  #pragma unroll
  for(int ks=0; ks<4; ++ks){
    bf16x8 Ah[4], Al[4], Bh[2], Bl[2];
    #pragma unroll
    for(int mi=0;mi<4;mi++){
      int o = mi*16 + l15;
      long off = (long)o*128 + ks*32 + lhi*8;
      Ah[mi] = *(const bf16x8*)(lw2Th + off);
      Al[mi] = *(const bf16x8*)(lw2Tl + off);
    }
    #pragma unroll
    for(int ni=0;ni<2;ni++){
      int t = n0 + ni*16 + l15;
      int byt = (t*256 + (ks*32 + lhi*8)*2) ^ ((t & 7) << 4);
      Bh[ni] = *(bf16x8*)((char*)zh + byt);
      Bl[ni] = *(bf16x8*)((char*)zl + byt);
    }
    #pragma unroll
    for(int mi=0;mi<4;mi++){
      #pragma unroll
      for(int ni=0;ni<2;ni++){
        acc[mi][ni] = mfma16(Ah[mi], Bh[ni], acc[mi][ni]);
        acc[mi][ni] = mfma16(Al[mi], Bh[ni], acc[mi][ni]);
        acc[mi][ni] = mfma16(Ah[mi], Bl[ni], acc[mi][ni]);
      }
    }
  }
  __syncthreads();
  float* fo = (float*)zz;
  #pragma unroll
  for(int mi=0;mi<4;mi++){
    #pragma unroll
    for(int ni=0;ni<2;ni++){
      #pragma unroll
      for(int r=0;r<4;r++){
        int o = mi*16 + lhi*4 + r;
        int tl = n0 + ni*16 + l15;
        fo[o*128 + (tl ^ ((o&7)<<2))] = acc[mi][ni][r];
      }
    }
  }
  __syncthreads();
  #pragma unroll
  for(int q=0;q<8;q++){
    int idx = q*256 + tid;
    int o = idx >> 5, tb = idx & 31;
    float4 rd = *(const float4*)(fo + o*128 + ((tb*4) ^ ((o&7)<<2)));
    float bias = lb2[o];
    u16 h0,h1,h2,h3,l0,l1,l2,l3;
    silu_split(rd.x + bias, h0, l0);
    silu_split(rd.y + bias, h1, l1);
    silu_split(rd.z + bias, h2, l2);
    silu_split(rd.w + bias, h3, l3);
    long base = ((long)b*64 + o)*TPAD_ + t0 + tb*4;
    *(uint2*)(hx + base) = make_uint2((unsigned)h0 | ((unsigned)h1<<16),
                                      (unsigned)h2 | ((unsigned)h3<<16));
    *(uint2*)(lx + base) = make_uint2((unsigned)l0 | ((unsigned)l1<<16),
                                      (unsigned)l2 | ((unsigned)l3<<16));
  }
}

// ---------------------------------------------------------------- forward DFT (LDS-staged, XCD-swizzled)
// xfp[s][(b*64+c)][j] = sum_{t in split s} h[b][c][t] * F_inv[j][t]
__global__ __launch_bounds__(256) void k_dftS(
    const u16* __restrict__ hx, const u16* __restrict__ lx,
    const u16* __restrict__ invFh, const u16* __restrict__ invFl,
    float* __restrict__ xfp)
{
  int wg  = blockIdx.x;
  int wgp = (wg & 7)*96 + (wg >> 3);   // bijective: same-XCD blocks share s
  int s = wgp >> 7, b = wgp & 127;
  int tid = threadIdx.x;
  int lane = tid & 63, w = tid >> 6;
  int l15 = lane & 15, lhi = lane >> 4;
  int n0 = w*32;
  __shared__ u16 ah[8192], al[8192];   // [c][128t] swizzled, 32 KB
  f32x4 acc[4][2];
  #pragma unroll
  for(int mi=0;mi<4;mi++){
    #pragma unroll
    for(int ni=0;ni<2;ni++) acc[mi][ni] = (f32x4){0.f,0.f,0.f,0.f};
  }
  int cst = tid >> 2, t4 = (tid & 3)*32;
  int swz = (cst & 7) << 4;
  for(int ch=0; ch<6; ++ch){
    long k0 = (long)s*768 + ch*128;
    if(ch) __syncthreads();
    { // stage tile: pure copy (activations already silu'd + split)
      const u16* ph = hx + ((long)b*64 + cst)*TPAD_ + k0 + t4;
      const u16* pl = lx + ((long)b*64 + cst)*TPAD_ + k0 + t4;
      #pragma unroll
      for(int q=0;q<4;q++){
        bf16x8 hv = __builtin_nontemporal_load((const bf16x8*)(ph + q*8));
        bf16x8 lv = __builtin_nontemporal_load((const bf16x8*)(pl + q*8));
        int byt = (cst*256 + (t4 + q*8)*2) ^ swz;
        *(bf16x8*)((char*)ah + byt) = hv;
        *(bf16x8*)((char*)al + byt) = lv;
      }
    }
    __syncthreads();
    #pragma unroll
    for(int ks=0; ks<4; ++ks){
      bf16x8 Ah[4], Al[4], Bh[2], Bl[2];
      #pragma unroll
      for(int mi=0;mi<4;mi++){
        int c = mi*16 + l15;
        int byt = (c*256 + (ks*32 + lhi*8)*2) ^ ((c & 7) << 4);
        Ah[mi] = *(bf16x8*)((char*)ah + byt);
        Al[mi] = *(bf16x8*)((char*)al + byt);
      }
      #pragma unroll
      for(int ni=0;ni<2;ni++){
        int j = n0 + ni*16 + l15;
        long off = (long)j*TPAD_ + k0 + ks*32 + lhi*8;
        Bh[ni] = *(const bf16x8*)(invFh + off);
        Bl[ni] = *(const bf16x8*)(invFl + off);
      }
      #pragma unroll
      for(int mi=0;mi<4;mi++){
        #pragma unroll
        for(int ni=0;ni<2;ni++){
          acc[mi][ni] = mfma16(Ah[mi], Bh[ni], acc[mi][ni]);
          acc[mi][ni] = mfma16(Al[mi], Bh[ni], acc[mi][ni]);
          acc[mi][ni] = mfma16(Ah[mi], Bl[ni], acc[mi][ni]);
        }
      }
    }
  }
  #pragma unroll
  for(int mi=0;mi<4;mi++){
    #pragma unroll
    for(int ni=0;ni<2;ni++){
      #pragma unroll
      for(int r=0;r<4;r++){
        int row = mi*16 + lhi*4 + r;
        int j = n0 + ni*16 + l15;
        xfp[((long)s*8192 + b*64 + row)*128 + j] = acc[mi][ni][r];
      }
    }
  }
}

// ---------------------------------------------------------------- spectral mix (6 splits)
__global__ __launch_bounds__(512) void k_spectral(
    const float* __restrict__ xfp, const float* __restrict__ wr_,
    const float* __restrict__ wi_, u16* __restrict__ coefh,
    u16* __restrict__ coefl, int l)
{
  int b = blockIdx.x, mh = blockIdx.y, tid = threadIdx.x;
  const float* wr = wr_ + (long)l*262144;
  const float* wi = wi_ + (long)l*262144;
  __shared__ float xr[64*36], xi[64*36];
  {
    int c = tid >> 3, mm0 = (tid & 7)*4;
    long base = ((long)(b*64 + c))*128 + mh*32 + mm0;
    float4 sr = make_float4(0.f,0.f,0.f,0.f), si = sr;
    #pragma unroll
    for(int s2=0;s2<KSPLIT;s2++){
      const float* p = xfp + (long)s2*1048576 + base;
      float4 a = *(const float4*)(p);
      float4 d = *(const float4*)(p + 64);
      sr.x += a.x; sr.y += a.y; sr.z += a.z; sr.w += a.w;
      si.x += d.x; si.y += d.y; si.z += d.z; si.w += d.w;
    }
    *(float4*)(xr + c*36 + mm0) = sr;
    *(float4*)(xi + c*36 + mm0) = si;
  }
  __syncthreads();
  int tx = tid & 15, ty = tid >> 4;
  float ar[2][2] = {{0.f,0.f},{0.f,0.f}};
  float ai[2][2] = {{0.f,0.f},{0.f,0.f}};
  #pragma unroll 2
  for(int c=0;c<64;c++){
    float x0r = xr[c*36 + 2*tx], x1r = xr[c*36 + 2*tx + 1];
    float x0i = xi[c*36 + 2*tx], x1i = xi[c*36 + 2*tx + 1];
    #pragma unroll
    for(int oi=0;oi<2;oi++){
      int o = 2*ty + oi;
      long wofs = ((long)(c*64 + o))*64 + mh*32 + 2*tx;
      float2 wrv = *(const float2*)(wr + wofs);
      float2 wiv = *(const float2*)(wi + wofs);
      ar[oi][0] += x0r*wrv.x - x0i*wiv.x;
      ai[oi][0] += x0r*wiv.x + x0i*wrv.x;
      ar[oi][1] += x1r*wrv.y - x1i*wiv.y;
      ai[oi][1] += x1r*wiv.y + x1i*wrv.y;
    }
  }
  #pragma unroll
  for(int j=0;j<2;j++){
    int m = mh*32 + 2*tx + j;
    float sc = (m==0) ? (1.0f/(float)TP_) : (2.0f/(float)TP_);
    #pragma unroll
    for(int oi=0;oi<2;oi++){
      int o = 2*ty + oi;
      long base = ((long)b*64 + o)*128;
      u16 h, l2;
      bf16_split(sc*ar[oi][j], h, l2);
      coefh[base + m] = h; coefl[base + m] = l2;
      bf16_split(sc*ai[oi][j], h, l2);
      coefh[base + 64 + m] = h; coefl[base + 64 + m] = l2;
    }
  }
}

// ---------------------------------------------------------------- inverse DFT + skip (R4 exact + NT streaming)
__global__ __launch_bounds__(256) void k_idft(
    u16* __restrict__ hx, u16* __restrict__ lx,
    const u16* __restrict__ coefh, const u16* __restrict__ coefl,
    const u16* __restrict__ fwdFh, const u16* __restrict__ fwdFl,
    const u16* __restrict__ skwh, const u16* __restrict__ skwl,
    const float* __restrict__ sb_, int lay, int last)
{
  int tt = blockIdx.x, b = blockIdx.y, tid = threadIdx.x;
  int t0 = tt*128;
  int lane = tid & 63, w = tid >> 6;
  int l15 = lane & 15, lhi = lane >> 4;
  int n0 = w*32;
  __shared__ u16 sh_[16384];           // hh[128t][64c], hl ; fo f32 aliases
  u16* hh = sh_;
  u16* hl = sh_ + 8192;
  { // stage h (already silu'd+split) transposed [t][c]
    int c0 = (tid & 31)*2, tg = tid >> 5;
    const u16* ph0 = hx + ((long)b*64 + c0)*TPAD_ + t0 + tg*16;
    const u16* ph1 = ph0 + TPAD_;
    const u16* pl0 = lx + ((long)b*64 + c0)*TPAD_ + t0 + tg*16;
    const u16* pl1 = pl0 + TPAD_;
    bf16x8 h0a = __builtin_nontemporal_load((const bf16x8*)(ph0));
    bf16x8 h0b = __builtin_nontemporal_load((const bf16x8*)(ph0 + 8));
    bf16x8 h1a = __builtin_nontemporal_load((const bf16x8*)(ph1));
    bf16x8 h1b = __builtin_nontemporal_load((const bf16x8*)(ph1 + 8));
    bf16x8 l0a = __builtin_nontemporal_load((const bf16x8*)(pl0));
    bf16x8 l0b = __builtin_nontemporal_load((const bf16x8*)(pl0 + 8));
    bf16x8 l1a = __builtin_nontemporal_load((const bf16x8*)(pl1));
    bf16x8 l1b = __builtin_nontemporal_load((const bf16x8*)(pl1 + 8));
    #pragma unroll
    for(int i=0;i<8;i++){
      int t = tg*16 + i;
      int byt = (t*128 + c0*2) ^ ((t & 7) << 4);
      *(unsigned*)((char*)hh + byt) =
        (unsigned)(u16)h0a[i] | ((unsigned)(u16)h1a[i] << 16);
      *(unsigned*)((char*)hl + byt) =
        (unsigned)(u16)l0a[i] | ((unsigned)(u16)l1a[i] << 16);
    }
    #pragma unroll
    for(int i=0;i<8;i++){
      int t = tg*16 + 8 + i;
      int byt = (t*128 + c0*2) ^ ((t & 7) << 4);
      *(unsigned*)((char*)hh + byt) =
        (unsigned)(u16)h0b[i] | ((unsigned)(u16)h1b[i] << 16);
      *(unsigned*)((char*)hl + byt) =
        (unsigned)(u16)l0b[i] | ((unsigned)(u16)l1b[i] << 16);
    }
  }
  f32x4 acc[4][2];
  #pragma unroll
  for(int mi=0;mi<4;mi++){
    #pragma unroll
    for(int ni=0;ni<2;ni++) acc[mi][ni] = (f32x4){0.f,0.f,0.f,0.f};
  }
  // phase 1: spectral, K=128 (coef x trig), global frags
  #pragma unroll
  for(int ks=0; ks<4; ++ks){
    bf16x8 Ah[4], Al[4], Bh[2], Bl[2];
    #pragma unroll
    for(int mi=0;mi<4;mi++){
      int o = mi*16 + l15;
      long off = ((long)(b*64 + o))*128 + ks*32 + lhi*8;
      Ah[mi] = *(const bf16x8*)(coefh + off);
      Al[mi] = *(const bf16x8*)(coefl + off);
    }
    #pragma unroll
    for(int ni=0;ni<2;ni++){
      int t = t0 + n0 + ni*16 + l15;
      long off = (long)t*128 + ks*32 + lhi*8;
      Bh[ni] = *(const bf16x8*)(fwdFh + off);
      Bl[ni] = *(const bf16x8*)(fwdFl + off);
    }
    #pragma unroll
    for(int mi=0;mi<4;mi++){
      #pragma unroll
      for(int ni=0;ni<2;ni++){
        acc[mi][ni] = mfma16(Ah[mi], Bh[ni], acc[mi][ni]);
        acc[mi][ni] = mfma16(Al[mi], Bh[ni], acc[mi][ni]);
        acc[mi][ni] = mfma16(Ah[mi], Bl[ni], acc[mi][ni]);
      }
    }
  }
  __syncthreads();
  // phase 2: skip GEMM, K=64 (skw x h), B from LDS
  #pragma unroll
  for(int ks=0; ks<2; ++ks){
    bf16x8 Ah[4], Al[4], Bh[2], Bl[2];
    #pragma unroll
    for(int mi=0;mi<4;mi++){
      int o = mi*16 + l15;
      long off = (long)lay*4096 + o*64 + ks*32 + lhi*8;
      Ah[mi] = *(const bf16x8*)(skwh + off);
      Al[mi] = *(const bf16x8*)(skwl + off);
    }
    #pragma unroll
    for(int ni=0;ni<2;ni++){
      int t = n0 + ni*16 + l15;
      int byt = (t*128 + (ks*32 + lhi*8)*2) ^ ((t & 7) << 4);
      Bh[ni] = *(bf16x8*)((char*)hh + byt);
      Bl[ni] = *(bf16x8*)((char*)hl + byt);
    }
    #pragma unroll
    for(int mi=0;mi<4;mi++){
      #pragma unroll
      for(int ni=0;ni<2;ni++){
        acc[mi][ni] = mfma16(Ah[mi], Bh[ni], acc[mi][ni]);
        acc[mi][ni] = mfma16(Al[mi], Bh[ni], acc[mi][ni]);
        acc[mi][ni] = mfma16(Ah[mi], Bl[ni], acc[mi][ni]);
      }
    }
  }
  __syncthreads();
  float* fo = (float*)sh_;   // [64 o][128 t], xor-swizzled
  #pragma unroll
  for(int mi=0;mi<4;mi++){
    #pragma unroll
    for(int ni=0;ni<2;ni++){
      #pragma unroll
      for(int r=0;r<4;r++){
        int o = mi*16 + lhi*4 + r;
        int tl = n0 + ni*16 + l15;
        fo[o*128 + (tl ^ ((o&7)<<2))] = acc[mi][ni][r];
      }
    }
  }
  __syncthreads();
  #pragma unroll
  for(int q=0;q<8;q++){
    int idx = q*256 + tid;
    int o = idx >> 5, tb = idx & 31;
    float4 rd = *(const float4*)(fo + o*128 + ((tb*4) ^ ((o&7)<<2)));
    float bias = sb_[lay*64 + o];
    float v[4] = {rd.x + bias, rd.y + bias, rd.z + bias, rd.w + bias};
    int tg = t0 + tb*4;
    #pragma unroll
    for(int j=0;j<4;j++){
      if(tg + j >= TP_) v[j] = 0.f;
      else if(!last)    v[j] = silu_f(v[j]);
    }
    u16 h0,h1,h2,h3,l0,l1,l2,l3;
    bf16_split(v[0], h0, l0);
    bf16_split(v[1], h1, l1);
    bf16_split(v[2], h2, l2);
    bf16_split(v[3], h3, l3);
    long base = ((long)b*64 + o)*TPAD_ + t0 + tb*4;
    u64 hv = (u64)((unsigned)h0 | ((unsigned)h1<<16)) |
             ((u64)((unsigned)h2 | ((unsigned)h3<<16)) << 32);
    u64 lv = (u64)((unsigned)l0 | ((unsigned)l1<<16)) |
             ((u64)((unsigned)l2 | ((unsigned)l3<<16)) << 32);
    __builtin_nontemporal_store(hv, (u64*)(hx + base));
    __builtin_nontemporal_store(lv, (u64*)(lx + base));
  }
}

// ---------------------------------------------------------------- projection (MFMA, R7 exact)
__global__ __launch_bounds__(256) void k_proj(
    const u16* __restrict__ hx, const u16* __restrict__ lx,
    const u16* __restrict__ pw1Th, const u16* __restrict__ pw1Tl,
    const float* __restrict__ pb1, const float* __restrict__ pw2,
    const float* __restrict__ pb2, float* __restrict__ out)
{
  int tt = blockIdx.x, b = blockIdx.y, tid = threadIdx.x;
  int t0 = tt*128;
  int lane = tid & 63, w = tid >> 6;
  int l15 = lane & 15, lhi = lane >> 4;
  __shared__ u16 sh_[16384];           // x tile transposed [128t][64c] h/l
  u16* hh = sh_;
  u16* hl = sh_ + 8192;
  {
    int c0 = (tid & 31)*2, tg = tid >> 5;
    const u16* ph0 = hx + ((long)b*64 + c0)*TPAD_ + t0 + tg*16;
    const u16* ph1 = ph0 + TPAD_;
    const u16* pl0 = lx + ((long)b*64 + c0)*TPAD_ + t0 + tg*16;
    const u16* pl1 = pl0 + TPAD_;
    bf16x8 h0a = *(const bf16x8*)(ph0),     h0b = *(const bf16x8*)(ph0 + 8);
    bf16x8 h1a = *(const bf16x8*)(ph1),     h1b = *(const bf16x8*)(ph1 + 8);
    bf16x8 l0a = *(const bf16x8*)(pl0),     l0b = *(const bf16x8*)(pl0 + 8);
    bf16x8 l1a = *(const bf16x8*)(pl1),     l1b = *(const bf16x8*)(pl1 + 8);
    #pragma unroll
    for(int i=0;i<8;i++){
      int t = tg*16 + i;
      int byt = (t*128 + c0*2) ^ ((t & 7) << 4);
      *(unsigned*)((char*)hh + byt) =
        (unsigned)(u16)h0a[i] | ((unsigned)(u16)h1a[i] << 16);
      *(unsigned*)((char*)hl + byt) =
        (unsigned)(u16)l0a[i] | ((unsigned)(u16)l1a[i] << 16);
    }
    #pragma unroll
    for(int i=0;i<8;i++){
      int t = tg*16 + 8 + i;
      int byt = (t*128 + c0*2) ^ ((t & 7) << 4);
      *(unsigned*)((char*)hh + byt) =
        (unsigned)(u16)h0b[i] | ((unsigned)(u16)h1b[i] << 16);
      *(unsigned*)((char*)hl + byt) =
        (unsigned)(u16)l0b[i] | ((unsigned)(u16)l1b[i] << 16);
    }
  }
  __syncthreads();
  f32x4 acc[2][8];
  #pragma unroll
  for(int mi=0;mi<2;mi++){
    #pragma unroll
    for(int ni=0;ni<8;ni++) acc[mi][ni] = (f32x4){0.f,0.f,0.f,0.f};
  }
  #pragma unroll
  for(int ks=0; ks<2; ++ks){
    bf16x8 Ah[2], Al[2], Bh[8], Bl[8];
    #pragma unroll
    for(int mi=0;mi<2;mi++){
      int t = w*32 + mi*16 + l15;
      int byt = (t*128 + (ks*32 + lhi*8)*2) ^ ((t & 7) << 4);
      Ah[mi] = *(bf16x8*)((char*)hh + byt);
      Al[mi] = *(bf16x8*)((char*)hl + byt);
    }
    #pragma unroll
    for(int ni=0;ni<8;ni++){
      long off = (long)(ni*16 + l15)*64 + ks*32 + lhi*8;
      Bh[ni] = *(const bf16x8*)(pw1Th + off);
      Bl[ni] = *(const bf16x8*)(pw1Tl + off);
    }
    #pragma unroll
    for(int mi=0;mi<2;mi++){
      #pragma unroll
      for(int ni=0;ni<8;ni++){
        acc[mi][ni] = mfma16(Ah[mi], Bh[ni], acc[mi][ni]);
        acc[mi][ni] = mfma16(Al[mi], Bh[ni], acc[mi][ni]);
        acc[mi][ni] = mfma16(Ah[mi], Bl[ni], acc[mi][ni]);
      }
    }
  }
  #pragma unroll
  for(int mi=0;mi<2;mi++){
    #pragma unroll
    for(int r=0;r<4;r++){
      int t = w*32 + mi*16 + lhi*4 + r;
      float s = 0.f;
      #pragma unroll
      for(int ni=0;ni<8;ni++){
        int d = ni*16 + l15;
        s += pw2[d] * silu_f(acc[mi][ni][r] + pb1[d]);
      }
      s += __shfl_xor(s, 1);
      s += __shfl_xor(s, 2);
      s += __shfl_xor(s, 4);
      s += __shfl_xor(s, 8);
      if(l15 == 0) out[(long)b*T_ + t0 + t] = s + pb2[0];
    }
  }
}

// ---------------------------------------------------------------- launch
extern "C" void kernel_launch(void* const* d_in, const int* in_sizes, int n_in,
                              void* d_out, int out_size, void* d_ws, size_t ws_size,
                              hipStream_t stream)
{
  const float* vterm = (const float*)d_in[0];
  const float* pp    = (const float*)d_in[1];
  const float* ew1   = (const float*)d_in[2];
  const float* eb1   = (const float*)d_in[3];
  const float* ew2   = (const float*)d_in[4];
  const float* eb2   = (const float*)d_in[5];
  const float* ew3   = (const float*)d_in[6];
  const float* eb3   = (const float*)d_in[7];
  const float* lw1   = (const float*)d_in[8];
  const float* lb1   = (const float*)d_in[9];
  const float* lw2   = (const float*)d_in[10];
  const float* lb2   = (const float*)d_in[11];
  const float* swr   = (const float*)d_in[12];
  const float* swi   = (const float*)d_in[13];
  const float* skw   = (const float*)d_in[14];
  const float* skb   = (const float*)d_in[15];
  const float* pw1   = (const float*)d_in[16];
  const float* pb1   = (const float*)d_in[17];
  const float* pw2   = (const float*)d_in[18];
  const float* pb2   = (const float*)d_in[19];
  float* out = (float*)d_out;

  u16* hx     = (u16*)d_ws;
  u16* lxp    = hx + 37748736;
  float* xfp  = (float*)(lxp + 37748736);
  u16* coefh  = (u16*)(xfp + 6291456);
  u16* coefl  = coefh + 1048576;
  u16* fwdFh  = coefl + 1048576;
  u16* fwdFl  = fwdFh + 589824;
  u16* invFh  = fwdFl + 589824;
  u16* invFl  = invFh + 589824;
  u16* skwh   = invFl + 589824;
  u16* skwl   = skwh + 16384;
  float* latb = (float*)coefh;   // dead before spectral writes coef
  u16* lw2Th  = coefl;           // dead before spectral writes coef
  u16* lw2Tl  = coefl + 8192;
  u16* pw1Th  = coefh;           // written by k_prep2 after coef is dead
  u16* pw1Tl  = coefh + 8192;

  k_tables<<<(TPAD_*64 + 255)/256, 256, 0, stream>>>(fwdFh, fwdFl, invFh, invFl);
  k_prep<<<(NL_*64*64 + 64*128 + 255)/256, 256, 0, stream>>>(
      skw, skwh, skwl, lw2, lw2Th, lw2Tl);
  k_embed<<<B_, 128, 0, stream>>>(pp, ew1, eb1, ew2, eb2, ew3, eb3, lw1, lb1, latb);
  k_lift<<<dim3(TPAD_/128, B_), 256, 0, stream>>>(
      vterm, latb, lw1, lw2Th, lw2Tl, lb2, hx, lxp);
  for(int l=0;l<NL_;l++){
    k_dftS<<<B_*KSPLIT, 256, 0, stream>>>(hx, lxp, invFh, invFl, xfp);
    k_spectral<<<dim3(B_, 2), 512, 0, stream>>>(xfp, swr, swi, coefh, coefl, l);
    k_idft<<<dim3(TPAD_/128, B_), 256, 0, stream>>>(
        hx, lxp, coefh, coefl, fwdFh, fwdFl, skwh, skwl, skb, l,
        (l==NL_-1) ? 1 : 0);
  }
  k_prep2<<<32, 256, 0, stream>>>(pw1, pw1Th, pw1Tl);
  k_proj<<<dim3(T_/128, B_), 256, 0, stream>>>(
      hx, lxp, pw1Th, pw1Tl, pb1, pw2, pb2, out);
}

// Round 10
// 1263.471 us; speedup vs baseline: 1.5509x; 1.2045x over previous
//
#include <hip/hip_runtime.h>
#include <math.h>

// MosfetFNO on MI355X — R8 consolidation minus the nontemporal regression.
// Pre-split silu'd activations hx/lx; LDS-staged split-K DFT with XCD swizzle;
// R4-exact idft; MFMA lift/proj. bf16 hi/lo 3-product emulation.
// B=128, T=4096, Tp=4506, TPAD=4608 = 6 splits x 768.
// ws (185,139,200 B):
//   hx,lx u16 [128][64][4608]   2x75,497,472 B
//   xfp   f32 [6][8192][128]      25,165,824 B
//   coefh/l u16 [128][64][128]  2x2,097,152 B  (latb aliases coefh, lw2T
//                               aliases coefl; pw1T aliases coefh at the end)
//   fwdFh/l u16 [4608][128] ; invFh/l u16 [128][4608] ; skwh/l u16 [4][64][64]
#define B_     128
#define T_     4096
#define TP_    4506
#define TPAD_  4608
#define KSPLIT 6
#define NL_    4

typedef __attribute__((ext_vector_type(8))) short bf16x8;
typedef __attribute__((ext_vector_type(4))) float f32x4;
typedef unsigned short u16;

__device__ __forceinline__ float silu_f(float x){
  return x / (1.0f + expf(-x));
}
__device__ __forceinline__ float gelu_f(float x){
  float u = x + 0.044715f*x*x*x;
  return 0.5f*x*(1.0f + tanhf(0.7978845608028654f*u));
}
__device__ __forceinline__ u16 bf16_rne(float f){
  unsigned u = __float_as_uint(f);
  unsigned r = u + 0x7FFFu + ((u >> 16) & 1u);
  return (u16)(r >> 16);
}
__device__ __forceinline__ void bf16_split(float f, u16& h, u16& l){
  h = bf16_rne(f);
  float fh = __uint_as_float(((unsigned)h) << 16);
  l = bf16_rne(f - fh);
}
__device__ __forceinline__ void silu_split(float v, u16& h, u16& l){
  float s = v / (1.0f + __expf(-v));
  bf16_split(s, h, l);
}
__device__ __forceinline__ f32x4 mfma16(bf16x8 a, bf16x8 b, f32x4 c){
  return __builtin_amdgcn_mfma_f32_16x16x32_bf16(a, b, c, 0, 0, 0);
}

// ---------------------------------------------------------------- tables
__global__ __launch_bounds__(256) void k_tables(u16* __restrict__ fwdFh,
    u16* __restrict__ fwdFl, u16* __restrict__ invFh, u16* __restrict__ invFl){
  int idx = blockIdx.x*256 + threadIdx.x;
  if(idx >= TPAD_*64) return;
  int t = idx >> 6, m = idx & 63;
  float c = 0.f, s = 0.f;
  if(t < TP_){
    int r = (int)(((long long)m * (long long)t) % TP_);
    double ang = 6.283185307179586476925287 * (double)r / (double)TP_;
    c = (float)cos(ang);
    s = -(float)sin(ang);
  }
  u16 ch, cl, sh, sl;
  bf16_split(c, ch, cl);
  bf16_split(s, sh, sl);
  fwdFh[t*128 + m] = ch;      fwdFl[t*128 + m] = cl;
  fwdFh[t*128 + 64 + m] = sh; fwdFl[t*128 + 64 + m] = sl;
  invFh[(long)m*TPAD_ + t] = ch;      invFl[(long)m*TPAD_ + t] = cl;
  invFh[(long)(64+m)*TPAD_ + t] = sh; invFl[(long)(64+m)*TPAD_ + t] = sl;
}

// skw + lw2^T -> bf16 hi/lo
__global__ __launch_bounds__(256) void k_prep(const float* __restrict__ skw,
    u16* __restrict__ skwh, u16* __restrict__ skwl,
    const float* __restrict__ lw2, u16* __restrict__ lw2Th,
    u16* __restrict__ lw2Tl){
  int i = blockIdx.x*256 + threadIdx.x;
  if(i < NL_*64*64){
    u16 h, l; bf16_split(skw[i], h, l);
    skwh[i] = h; skwl[i] = l;
  } else if(i < NL_*64*64 + 64*128){
    int j = i - NL_*64*64;
    int w = j >> 7, d = j & 127;
    u16 h, l; bf16_split(lw2[d*64 + w], h, l);
    lw2Th[j] = h; lw2Tl[j] = l;
  }
}

// pw1^T -> bf16 hi/lo (after last layer; coef region dead)
__global__ __launch_bounds__(256) void k_prep2(const float* __restrict__ pw1,
    u16* __restrict__ pw1Th, u16* __restrict__ pw1Tl){
  int i = blockIdx.x*256 + threadIdx.x;
  if(i >= 64*128) return;
  int d = i >> 6, w = i & 63;
  u16 h, l; bf16_split(pw1[w*128 + d], h, l);
  pw1Th[i] = h; pw1Tl[i] = l;
}

// ---------------------------------------------------------------- embed
__global__ __launch_bounds__(128) void k_embed(
    const float* __restrict__ pp,
    const float* __restrict__ ew1, const float* __restrict__ eb1,
    const float* __restrict__ ew2, const float* __restrict__ eb2,
    const float* __restrict__ ew3, const float* __restrict__ eb3,
    const float* __restrict__ lw1, const float* __restrict__ lb1,
    float* __restrict__ latb)
{
  int b = blockIdx.x, tid = threadIdx.x;
  __shared__ float p[64], h1[128], h2[128], e[32];
  if(tid < 64) p[tid] = pp[b*64 + tid];
  __syncthreads();
  {
    float z = eb1[tid];
    for(int j=0;j<64;j++) z += p[j]*ew1[j*128 + tid];
    h1[tid] = gelu_f(z);
  }
  __syncthreads();
  {
    float z = eb2[tid];
    for(int j=0;j<128;j++) z += h1[j]*ew2[j*128 + tid];
    h2[tid] = gelu_f(z);
  }
  __syncthreads();
  if(tid < 32){
    float z = eb3[tid];
    for(int j=0;j<128;j++) z += h2[j]*ew3[j*32 + tid];
    e[tid] = tanhf(z);
  }
  __syncthreads();
  {
    float v = lb1[tid];
    for(int c=0;c<32;c++) v += e[c]*lw1[(4+c)*128 + tid];
    latb[b*128 + tid] = v;
  }
}

// ---------------------------------------------------------------- lift (MFMA, R4 exact)
__global__ __launch_bounds__(256) void k_lift(
    const float* __restrict__ vterm, const float* __restrict__ latb,
    const float* __restrict__ lw1,  const u16* __restrict__ lw2Th,
    const u16* __restrict__ lw2Tl, const float* __restrict__ lb2,
    u16* __restrict__ hx, u16* __restrict__ lx)
{
  int tt = blockIdx.x, b = blockIdx.y, tid = threadIdx.x;
  int t0 = tt*128;
  if(t0 >= T_){
    int r = tid >> 2, t00 = (tid & 3)*32;
    bf16x8 z8 = (bf16x8){0,0,0,0,0,0,0,0};
    long base = ((long)b*64 + r)*TPAD_ + t0 + t00;
    #pragma unroll
    for(int q=0;q<4;q++){
      *(bf16x8*)(hx + base + q*8) = z8;
      *(bf16x8*)(lx + base + q*8) = z8;
    }
    return;
  }
  __shared__ u16 zz[32768];
  u16* zh = zz;
  u16* zl = zz + 16384;
  __shared__ float vt[512], lw1c[512], latbs[128];
  if(tid < 128){
    int c = tid >> 5, tc = (tid & 31)*4;
    *(float4*)(vt + c*128 + tc) =
      *(const float4*)(vterm + ((long)b*4 + c)*T_ + t0 + tc);
  } else {
    int i = (tid - 128)*4;
    *(float4*)(lw1c + i) = *(const float4*)(lw1 + i);
  }
  if(tid < 32)
    *(float4*)(latbs + tid*4) = *(const float4*)(latb + b*128 + tid*4);
  __syncthreads();
  {
    int t = tid >> 1, dh = (tid & 1)*64;
    float v0 = vt[t], v1 = vt[128+t], v2 = vt[256+t], v3 = vt[384+t];
    int swz = (t & 7) << 4;
    #pragma unroll
    for(int q=0;q<16;q++){
      int d0 = dh + q*4;
      float4 w0 = *(const float4*)(lw1c + d0);
      float4 w1 = *(const float4*)(lw1c + 128 + d0);
      float4 w2 = *(const float4*)(lw1c + 256 + d0);
      float4 w3 = *(const float4*)(lw1c + 384 + d0);
      float4 lb = *(const float4*)(latbs + d0);
      u16 h0,h1,h2,h3,l0,l1,l2,l3;
      silu_split(lb.x + w0.x*v0 + w1.x*v1 + w2.x*v2 + w3.x*v3, h0, l0);
      silu_split(lb.y + w0.y*v0 + w1.y*v1 + w2.y*v2 + w3.y*v3, h1, l1);
      silu_split(lb.z + w0.z*v0 + w1.z*v1 + w2.z*v2 + w3.z*v3, h2, l2);
      silu_split(lb.w + w0.w*v0 + w1.w*v1 + w2.w*v2 + w3.w*v3, h3, l3);
      int byt = (t*256 + d0*2) ^ swz;
      uint2 hv = make_uint2((unsigned)h0 | ((unsigned)h1<<16),
                            (unsigned)h2 | ((unsigned)h3<<16));
      uint2 lv = make_uint2((unsigned)l0 | ((unsigned)l1<<16),
                            (unsigned)l2 | ((unsigned)l3<<16));
      *(uint2*)((char*)zh + byt) = hv;
      *(uint2*)((char*)zl + byt) = lv;
    }
  }
  __syncthreads();
  int lane = tid & 63, w = tid >> 6;
  int l15 = lane & 15, lhi = lane >> 4;
  int n0 = w*32;
  f32x4 acc[4][2];
  #pragma unroll
  for(int mi=0;mi<4;mi++){
    #pragma unroll
    for(int ni=0;ni<2;ni++) acc[mi][ni] = (f32x4){0.f,0.f,0.f,0.f};
  }
  #pragma unroll
  for(int ks=0; ks<4; ++ks){
    bf16x8 Ah[4], Al[4], Bh[2], Bl[2];
    #pragma unroll
    for(int mi=0;mi<4;mi++){
      int o = mi*16 + l15;
      long off = (long)o*128 + ks*32 + lhi*8;
      Ah[mi] = *(const bf16x8*)(lw2Th + off);
      Al[mi] = *(const bf16x8*)(lw2Tl + off);
    }
    #pragma unroll
    for(int ni=0;ni<2;ni++){
      int t = n0 + ni*16 + l15;
      int byt = (t*256 + (ks*32 + lhi*8)*2) ^ ((t & 7) << 4);
      Bh[ni] = *(bf16x8*)((char*)zh + byt);
      Bl[ni] = *(bf16x8*)((char*)zl + byt);
    }
    #pragma unroll
    for(int mi=0;mi<4;mi++){
      #pragma unroll
      for(int ni=0;ni<2;ni++){
        acc[mi][ni] = mfma16(Ah[mi], Bh[ni], acc[mi][ni]);
        acc[mi][ni] = mfma16(Al[mi], Bh[ni], acc[mi][ni]);
        acc[mi][ni] = mfma16(Ah[mi], Bl[ni], acc[mi][ni]);
      }
    }
  }
  __syncthreads();
  float* fo = (float*)zz;
  #pragma unroll
  for(int mi=0;mi<4;mi++){
    #pragma unroll
    for(int ni=0;ni<2;ni++){
      #pragma unroll
      for(int r=0;r<4;r++){
        int o = mi*16 + lhi*4 + r;
        int tl = n0 + ni*16 + l15;
        fo[o*128 + (tl ^ ((o&7)<<2))] = acc[mi][ni][r];
      }
    }
  }
  __syncthreads();
  #pragma unroll
  for(int q=0;q<8;q++){
    int idx = q*256 + tid;
    int o = idx >> 5, tb = idx & 31;
    float4 rd = *(const float4*)(fo + o*128 + ((tb*4) ^ ((o&7)<<2)));
    float bias = lb2[o];
    u16 h0,h1,h2,h3,l0,l1,l2,l3;
    silu_split(rd.x + bias, h0, l0);
    silu_split(rd.y + bias, h1, l1);
    silu_split(rd.z + bias, h2, l2);
    silu_split(rd.w + bias, h3, l3);
    long base = ((long)b*64 + o)*TPAD_ + t0 + tb*4;
    *(uint2*)(hx + base) = make_uint2((unsigned)h0 | ((unsigned)h1<<16),
                                      (unsigned)h2 | ((unsigned)h3<<16));
    *(uint2*)(lx + base) = make_uint2((unsigned)l0 | ((unsigned)l1<<16),
                                      (unsigned)l2 | ((unsigned)l3<<16));
  }
}

// ---------------------------------------------------------------- forward DFT (LDS-staged, XCD-swizzled)
// xfp[s][(b*64+c)][j] = sum_{t in split s} h[b][c][t] * F_inv[j][t]
__global__ __launch_bounds__(256) void k_dftS(
    const u16* __restrict__ hx, const u16* __restrict__ lx,
    const u16* __restrict__ invFh, const u16* __restrict__ invFl,
    float* __restrict__ xfp)
{
  int wg  = blockIdx.x;
  int wgp = (wg & 7)*96 + (wg >> 3);   // bijective: same-XCD blocks share s
  int s = wgp >> 7, b = wgp & 127;
  int tid = threadIdx.x;
  int lane = tid & 63, w = tid >> 6;
  int l15 = lane & 15, lhi = lane >> 4;
  int n0 = w*32;
  __shared__ u16 ah[8192], al[8192];   // [c][128t] swizzled, 32 KB
  f32x4 acc[4][2];
  #pragma unroll
  for(int mi=0;mi<4;mi++){
    #pragma unroll
    for(int ni=0;ni<2;ni++) acc[mi][ni] = (f32x4){0.f,0.f,0.f,0.f};
  }
  int cst = tid >> 2, t4 = (tid & 3)*32;
  int swz = (cst & 7) << 4;
  for(int ch=0; ch<6; ++ch){
    long k0 = (long)s*768 + ch*128;
    if(ch) __syncthreads();
    { // stage tile: pure copy (activations already silu'd + split)
      const u16* ph = hx + ((long)b*64 + cst)*TPAD_ + k0 + t4;
      const u16* pl = lx + ((long)b*64 + cst)*TPAD_ + k0 + t4;
      #pragma unroll
      for(int q=0;q<4;q++){
        bf16x8 hv = *(const bf16x8*)(ph + q*8);
        bf16x8 lv = *(const bf16x8*)(pl + q*8);
        int byt = (cst*256 + (t4 + q*8)*2) ^ swz;
        *(bf16x8*)((char*)ah + byt) = hv;
        *(bf16x8*)((char*)al + byt) = lv;
      }
    }
    __syncthreads();
    #pragma unroll
    for(int ks=0; ks<4; ++ks){
      bf16x8 Ah[4], Al[4], Bh[2], Bl[2];
      #pragma unroll
      for(int mi=0;mi<4;mi++){
        int c = mi*16 + l15;
        int byt = (c*256 + (ks*32 + lhi*8)*2) ^ ((c & 7) << 4);
        Ah[mi] = *(bf16x8*)((char*)ah + byt);
        Al[mi] = *(bf16x8*)((char*)al + byt);
      }
      #pragma unroll
      for(int ni=0;ni<2;ni++){
        int j = n0 + ni*16 + l15;
        long off = (long)j*TPAD_ + k0 + ks*32 + lhi*8;
        Bh[ni] = *(const bf16x8*)(invFh + off);
        Bl[ni] = *(const bf16x8*)(invFl + off);
      }
      #pragma unroll
      for(int mi=0;mi<4;mi++){
        #pragma unroll
        for(int ni=0;ni<2;ni++){
          acc[mi][ni] = mfma16(Ah[mi], Bh[ni], acc[mi][ni]);
          acc[mi][ni] = mfma16(Al[mi], Bh[ni], acc[mi][ni]);
          acc[mi][ni] = mfma16(Ah[mi], Bl[ni], acc[mi][ni]);
        }
      }
    }
  }
  #pragma unroll
  for(int mi=0;mi<4;mi++){
    #pragma unroll
    for(int ni=0;ni<2;ni++){
      #pragma unroll
      for(int r=0;r<4;r++){
        int row = mi*16 + lhi*4 + r;
        int j = n0 + ni*16 + l15;
        xfp[((long)s*8192 + b*64 + row)*128 + j] = acc[mi][ni][r];
      }
    }
  }
}

// ---------------------------------------------------------------- spectral mix (6 splits)
__global__ __launch_bounds__(512) void k_spectral(
    const float* __restrict__ xfp, const float* __restrict__ wr_,
    const float* __restrict__ wi_, u16* __restrict__ coefh,
    u16* __restrict__ coefl, int l)
{
  int b = blockIdx.x, mh = blockIdx.y, tid = threadIdx.x;
  const float* wr = wr_ + (long)l*262144;
  const float* wi = wi_ + (long)l*262144;
  __shared__ float xr[64*36], xi[64*36];
  {
    int c = tid >> 3, mm0 = (tid & 7)*4;
    long base = ((long)(b*64 + c))*128 + mh*32 + mm0;
    float4 sr = make_float4(0.f,0.f,0.f,0.f), si = sr;
    #pragma unroll
    for(int s2=0;s2<KSPLIT;s2++){
      const float* p = xfp + (long)s2*1048576 + base;
      float4 a = *(const float4*)(p);
      float4 d = *(const float4*)(p + 64);
      sr.x += a.x; sr.y += a.y; sr.z += a.z; sr.w += a.w;
      si.x += d.x; si.y += d.y; si.z += d.z; si.w += d.w;
    }
    *(float4*)(xr + c*36 + mm0) = sr;
    *(float4*)(xi + c*36 + mm0) = si;
  }
  __syncthreads();
  int tx = tid & 15, ty = tid >> 4;
  float ar[2][2] = {{0.f,0.f},{0.f,0.f}};
  float ai[2][2] = {{0.f,0.f},{0.f,0.f}};
  #pragma unroll 2
  for(int c=0;c<64;c++){
    float x0r = xr[c*36 + 2*tx], x1r = xr[c*36 + 2*tx + 1];
    float x0i = xi[c*36 + 2*tx], x1i = xi[c*36 + 2*tx + 1];
    #pragma unroll
    for(int oi=0;oi<2;oi++){
      int o = 2*ty + oi;
      long wofs = ((long)(c*64 + o))*64 + mh*32 + 2*tx;
      float2 wrv = *(const float2*)(wr + wofs);
      float2 wiv = *(const float2*)(wi + wofs);
      ar[oi][0] += x0r*wrv.x - x0i*wiv.x;
      ai[oi][0] += x0r*wiv.x + x0i*wrv.x;
      ar[oi][1] += x1r*wrv.y - x1i*wiv.y;
      ai[oi][1] += x1r*wiv.y + x1i*wrv.y;
    }
  }
  #pragma unroll
  for(int j=0;j<2;j++){
    int m = mh*32 + 2*tx + j;
    float sc = (m==0) ? (1.0f/(float)TP_) : (2.0f/(float)TP_);
    #pragma unroll
    for(int oi=0;oi<2;oi++){
      int o = 2*ty + oi;
      long base = ((long)b*64 + o)*128;
      u16 h, l2;
      bf16_split(sc*ar[oi][j], h, l2);
      coefh[base + m] = h; coefl[base + m] = l2;
      bf16_split(sc*ai[oi][j], h, l2);
      coefh[base + 64 + m] = h; coefl[base + 64 + m] = l2;
    }
  }
}

// ---------------------------------------------------------------- inverse DFT + skip (R4 exact)
__global__ __launch_bounds__(256) void k_idft(
    u16* __restrict__ hx, u16* __restrict__ lx,
    const u16* __restrict__ coefh, const u16* __restrict__ coefl,
    const u16* __restrict__ fwdFh, const u16* __restrict__ fwdFl,
    const u16* __restrict__ skwh, const u16* __restrict__ skwl,
    const float* __restrict__ sb_, int lay, int last)
{
  int tt = blockIdx.x, b = blockIdx.y, tid = threadIdx.x;
  int t0 = tt*128;
  int lane = tid & 63, w = tid >> 6;
  int l15 = lane & 15, lhi = lane >> 4;
  int n0 = w*32;
  __shared__ u16 sh_[16384];           // hh[128t][64c], hl ; fo f32 aliases
  u16* hh = sh_;
  u16* hl = sh_ + 8192;
  { // stage h (already silu'd+split) transposed [t][c]
    int c0 = (tid & 31)*2, tg = tid >> 5;
    const u16* ph0 = hx + ((long)b*64 + c0)*TPAD_ + t0 + tg*16;
    const u16* ph1 = ph0 + TPAD_;
    const u16* pl0 = lx + ((long)b*64 + c0)*TPAD_ + t0 + tg*16;
    const u16* pl1 = pl0 + TPAD_;
    bf16x8 h0a = *(const bf16x8*)(ph0),     h0b = *(const bf16x8*)(ph0 + 8);
    bf16x8 h1a = *(const bf16x8*)(ph1),     h1b = *(const bf16x8*)(ph1 + 8);
    bf16x8 l0a = *(const bf16x8*)(pl0),     l0b = *(const bf16x8*)(pl0 + 8);
    bf16x8 l1a = *(const bf16x8*)(pl1),     l1b = *(const bf16x8*)(pl1 + 8);
    #pragma unroll
    for(int i=0;i<8;i++){
      int t = tg*16 + i;
      int byt = (t*128 + c0*2) ^ ((t & 7) << 4);
      *(unsigned*)((char*)hh + byt) =
        (unsigned)(u16)h0a[i] | ((unsigned)(u16)h1a[i] << 16);
      *(unsigned*)((char*)hl + byt) =
        (unsigned)(u16)l0a[i] | ((unsigned)(u16)l1a[i] << 16);
    }
    #pragma unroll
    for(int i=0;i<8;i++){
      int t = tg*16 + 8 + i;
      int byt = (t*128 + c0*2) ^ ((t & 7) << 4);
      *(unsigned*)((char*)hh + byt) =
        (unsigned)(u16)h0b[i] | ((unsigned)(u16)h1b[i] << 16);
      *(unsigned*)((char*)hl + byt) =
        (unsigned)(u16)l0b[i] | ((unsigned)(u16)l1b[i] << 16);
    }
  }
  f32x4 acc[4][2];
  #pragma unroll
  for(int mi=0;mi<4;mi++){
    #pragma unroll
    for(int ni=0;ni<2;ni++) acc[mi][ni] = (f32x4){0.f,0.f,0.f,0.f};
  }
  // phase 1: spectral, K=128 (coef x trig), global frags
  #pragma unroll
  for(int ks=0; ks<4; ++ks){
    bf16x8 Ah[4], Al[4], Bh[2], Bl[2];
    #pragma unroll
    for(int mi=0;mi<4;mi++){
      int o = mi*16 + l15;
      long off = ((long)(b*64 + o))*128 + ks*32 + lhi*8;
      Ah[mi] = *(const bf16x8*)(coefh + off);
      Al[mi] = *(const bf16x8*)(coefl + off);
    }
    #pragma unroll
    for(int ni=0;ni<2;ni++){
      int t = t0 + n0 + ni*16 + l15;
      long off = (long)t*128 + ks*32 + lhi*8;
      Bh[ni] = *(const bf16x8*)(fwdFh + off);
      Bl[ni] = *(const bf16x8*)(fwdFl + off);
    }
    #pragma unroll
    for(int mi=0;mi<4;mi++){
      #pragma unroll
      for(int ni=0;ni<2;ni++){
        acc[mi][ni] = mfma16(Ah[mi], Bh[ni], acc[mi][ni]);
        acc[mi][ni] = mfma16(Al[mi], Bh[ni], acc[mi][ni]);
        acc[mi][ni] = mfma16(Ah[mi], Bl[ni], acc[mi][ni]);
      }
    }
  }
  __syncthreads();
  // phase 2: skip GEMM, K=64 (skw x h), B from LDS
  #pragma unroll
  for(int ks=0; ks<2; ++ks){
    bf16x8 Ah[4], Al[4], Bh[2], Bl[2];
    #pragma unroll
    for(int mi=0;mi<4;mi++){
      int o = mi*16 + l15;
      long off = (long)lay*4096 + o*64 + ks*32 + lhi*8;
      Ah[mi] = *(const bf16x8*)(skwh + off);
      Al[mi] = *(const bf16x8*)(skwl + off);
    }
    #pragma unroll
    for(int ni=0;ni<2;ni++){
      int t = n0 + ni*16 + l15;
      int byt = (t*128 + (ks*32 + lhi*8)*2) ^ ((t & 7) << 4);
      Bh[ni] = *(bf16x8*)((char*)hh + byt);
      Bl[ni] = *(bf16x8*)((char*)hl + byt);
    }
    #pragma unroll
    for(int mi=0;mi<4;mi++){
      #pragma unroll
      for(int ni=0;ni<2;ni++){
        acc[mi][ni] = mfma16(Ah[mi], Bh[ni], acc[mi][ni]);
        acc[mi][ni] = mfma16(Al[mi], Bh[ni], acc[mi][ni]);
        acc[mi][ni] = mfma16(Ah[mi], Bl[ni], acc[mi][ni]);
      }
    }
  }
  __syncthreads();
  float* fo = (float*)sh_;   // [64 o][128 t], xor-swizzled
  #pragma unroll
  for(int mi=0;mi<4;mi++){
    #pragma unroll
    for(int ni=0;ni<2;ni++){
      #pragma unroll
      for(int r=0;r<4;r++){
        int o = mi*16 + lhi*4 + r;
        int tl = n0 + ni*16 + l15;
        fo[o*128 + (tl ^ ((o&7)<<2))] = acc[mi][ni][r];
      }
    }
  }
  __syncthreads();
  #pragma unroll
  for(int q=0;q<8;q++){
    int idx = q*256 + tid;
    int o = idx >> 5, tb = idx & 31;
    float4 rd = *(const float4*)(fo + o*128 + ((tb*4) ^ ((o&7)<<2)));
    float bias = sb_[lay*64 + o];
    float v[4] = {rd.x + bias, rd.y + bias, rd.z + bias, rd.w + bias};
    int tg = t0 + tb*4;
    #pragma unroll
    for(int j=0;j<4;j++){
      if(tg + j >= TP_) v[j] = 0.f;
      else if(!last)    v[j] = silu_f(v[j]);
    }
    u16 h0,h1,h2,h3,l0,l1,l2,l3;
    bf16_split(v[0], h0, l0);
    bf16_split(v[1], h1, l1);
    bf16_split(v[2], h2, l2);
    bf16_split(v[3], h3, l3);
    long base = ((long)b*64 + o)*TPAD_ + t0 + tb*4;
    *(uint2*)(hx + base) = make_uint2((unsigned)h0 | ((unsigned)h1<<16),
                                      (unsigned)h2 | ((unsigned)h3<<16));
    *(uint2*)(lx + base) = make_uint2((unsigned)l0 | ((unsigned)l1<<16),
                                      (unsigned)l2 | ((unsigned)l3<<16));
  }
}

// ---------------------------------------------------------------- projection (MFMA, R7 exact)
__global__ __launch_bounds__(256) void k_proj(
    const u16* __restrict__ hx, const u16* __restrict__ lx,
    const u16* __restrict__ pw1Th, const u16* __restrict__ pw1Tl,
    const float* __restrict__ pb1, const float* __restrict__ pw2,
    const float* __restrict__ pb2, float* __restrict__ out)
{
  int tt = blockIdx.x, b = blockIdx.y, tid = threadIdx.x;
  int t0 = tt*128;
  int lane = tid & 63, w = tid >> 6;
  int l15 = lane & 15, lhi = lane >> 4;
  __shared__ u16 sh_[16384];           // x tile transposed [128t][64c] h/l
  u16* hh = sh_;
  u16* hl = sh_ + 8192;
  {
    int c0 = (tid & 31)*2, tg = tid >> 5;
    const u16* ph0 = hx + ((long)b*64 + c0)*TPAD_ + t0 + tg*16;
    const u16* ph1 = ph0 + TPAD_;
    const u16* pl0 = lx + ((long)b*64 + c0)*TPAD_ + t0 + tg*16;
    const u16* pl1 = pl0 + TPAD_;
    bf16x8 h0a = *(const bf16x8*)(ph0),     h0b = *(const bf16x8*)(ph0 + 8);
    bf16x8 h1a = *(const bf16x8*)(ph1),     h1b = *(const bf16x8*)(ph1 + 8);
    bf16x8 l0a = *(const bf16x8*)(pl0),     l0b = *(const bf16x8*)(pl0 + 8);
    bf16x8 l1a = *(const bf16x8*)(pl1),     l1b = *(const bf16x8*)(pl1 + 8);
    #pragma unroll
    for(int i=0;i<8;i++){
      int t = tg*16 + i;
      int byt = (t*128 + c0*2) ^ ((t & 7) << 4);
      *(unsigned*)((char*)hh + byt) =
        (unsigned)(u16)h0a[i] | ((unsigned)(u16)h1a[i] << 16);
      *(unsigned*)((char*)hl + byt) =
        (unsigned)(u16)l0a[i] | ((unsigned)(u16)l1a[i] << 16);
    }
    #pragma unroll
    for(int i=0;i<8;i++){
      int t = tg*16 + 8 + i;
      int byt = (t*128 + c0*2) ^ ((t & 7) << 4);
      *(unsigned*)((char*)hh + byt) =
        (unsigned)(u16)h0b[i] | ((unsigned)(u16)h1b[i] << 16);
      *(unsigned*)((char*)hl + byt) =
        (unsigned)(u16)l0b[i] | ((unsigned)(u16)l1b[i] << 16);
    }
  }
  __syncthreads();
  f32x4 acc[2][8];
  #pragma unroll
  for(int mi=0;mi<2;mi++){
    #pragma unroll
    for(int ni=0;ni<8;ni++) acc[mi][ni] = (f32x4){0.f,0.f,0.f,0.f};
  }
  #pragma unroll
  for(int ks=0; ks<2; ++ks){
    bf16x8 Ah[2], Al[2], Bh[8], Bl[8];
    #pragma unroll
    for(int mi=0;mi<2;mi++){
      int t = w*32 + mi*16 + l15;
      int byt = (t*128 + (ks*32 + lhi*8)*2) ^ ((t & 7) << 4);
      Ah[mi] = *(bf16x8*)((char*)hh + byt);
      Al[mi] = *(bf16x8*)((char*)hl + byt);
    }
    #pragma unroll
    for(int ni=0;ni<8;ni++){
      long off = (long)(ni*16 + l15)*64 + ks*32 + lhi*8;
      Bh[ni] = *(const bf16x8*)(pw1Th + off);
      Bl[ni] = *(const bf16x8*)(pw1Tl + off);
    }
    #pragma unroll
    for(int mi=0;mi<2;mi++){
      #pragma unroll
      for(int ni=0;ni<8;ni++){
        acc[mi][ni] = mfma16(Ah[mi], Bh[ni], acc[mi][ni]);
        acc[mi][ni] = mfma16(Al[mi], Bh[ni], acc[mi][ni]);
        acc[mi][ni] = mfma16(Ah[mi], Bl[ni], acc[mi][ni]);
      }
    }
  }
  #pragma unroll
  for(int mi=0;mi<2;mi++){
    #pragma unroll
    for(int r=0;r<4;r++){
      int t = w*32 + mi*16 + lhi*4 + r;
      float s = 0.f;
      #pragma unroll
      for(int ni=0;ni<8;ni++){
        int d = ni*16 + l15;
        s += pw2[d] * silu_f(acc[mi][ni][r] + pb1[d]);
      }
      s += __shfl_xor(s, 1);
      s += __shfl_xor(s, 2);
      s += __shfl_xor(s, 4);
      s += __shfl_xor(s, 8);
      if(l15 == 0) out[(long)b*T_ + t0 + t] = s + pb2[0];
    }
  }
}

// ---------------------------------------------------------------- launch
extern "C" void kernel_launch(void* const* d_in, const int* in_sizes, int n_in,
                              void* d_out, int out_size, void* d_ws, size_t ws_size,
                              hipStream_t stream)
{
  const float* vterm = (const float*)d_in[0];
  const float* pp    = (const float*)d_in[1];
  const float* ew1   = (const float*)d_in[2];
  const float* eb1   = (const float*)d_in[3];
  const float* ew2   = (const float*)d_in[4];
  const float* eb2   = (const float*)d_in[5];
  const float* ew3   = (const float*)d_in[6];
  const float* eb3   = (const float*)d_in[7];
  const float* lw1   = (const float*)d_in[8];
  const float* lb1   = (const float*)d_in[9];
  const float* lw2   = (const float*)d_in[10];
  const float* lb2   = (const float*)d_in[11];
  const float* swr   = (const float*)d_in[12];
  const float* swi   = (const float*)d_in[13];
  const float* skw   = (const float*)d_in[14];
  const float* skb   = (const float*)d_in[15];
  const float* pw1   = (const float*)d_in[16];
  const float* pb1   = (const float*)d_in[17];
  const float* pw2   = (const float*)d_in[18];
  const float* pb2   = (const float*)d_in[19];
  float* out = (float*)d_out;

  u16* hx     = (u16*)d_ws;
  u16* lxp    = hx + 37748736;
  float* xfp  = (float*)(lxp + 37748736);
  u16* coefh  = (u16*)(xfp + 6291456);
  u16* coefl  = coefh + 1048576;
  u16* fwdFh  = coefl + 1048576;
  u16* fwdFl  = fwdFh + 589824;
  u16* invFh  = fwdFl + 589824;
  u16* invFl  = invFh + 589824;
  u16* skwh   = invFl + 589824;
  u16* skwl   = skwh + 16384;
  float* latb = (float*)coefh;   // dead before spectral writes coef
  u16* lw2Th  = coefl;           // dead before spectral writes coef
  u16* lw2Tl  = coefl + 8192;
  u16* pw1Th  = coefh;           // written by k_prep2 after coef is dead
  u16* pw1Tl  = coefh + 8192;

  k_tables<<<(TPAD_*64 + 255)/256, 256, 0, stream>>>(fwdFh, fwdFl, invFh, invFl);
  k_prep<<<(NL_*64*64 + 64*128 + 255)/256, 256, 0, stream>>>(
      skw, skwh, skwl, lw2, lw2Th, lw2Tl);
  k_embed<<<B_, 128, 0, stream>>>(pp, ew1, eb1, ew2, eb2, ew3, eb3, lw1, lb1, latb);
  k_lift<<<dim3(TPAD_/128, B_), 256, 0, stream>>>(
      vterm, latb, lw1, lw2Th, lw2Tl, lb2, hx, lxp);
  for(int l=0;l<NL_;l++){
    k_dftS<<<B_*KSPLIT, 256, 0, stream>>>(hx, lxp, invFh, invFl, xfp);
    k_spectral<<<dim3(B_, 2), 512, 0, stream>>>(xfp, swr, swi, coefh, coefl, l);
    k_idft<<<dim3(TPAD_/128, B_), 256, 0, stream>>>(
        hx, lxp, coefh, coefl, fwdFh, fwdFl, skwh, skwl, skb, l,
        (l==NL_-1) ? 1 : 0);
  }
  k_prep2<<<32, 256, 0, stream>>>(pw1, pw1Th, pw1Tl);
  k_proj<<<dim3(T_/128, B_), 256, 0, stream>>>(
      hx, lxp, pw1Th, pw1Tl, pb1, pw2, pb2, out);
}

// Round 11
// 1191.621 us; speedup vs baseline: 1.6444x; 1.0603x over previous
//
#include <hip/hip_runtime.h>
#include <math.h>

// MosfetFNO on MI355X — R10 + idft staging coalescing (swznib swizzle) and
// fast-silu epilogues. Pre-split silu'd activations hx/lx; LDS-staged split-K
// DFT with XCD swizzle; MFMA lift/proj. bf16 hi/lo 3-product emulation.
// B=128, T=4096, Tp=4506, TPAD=4608 = 6 splits x 768.
// ws (185,139,200 B):
//   hx,lx u16 [128][64][4608]   2x75,497,472 B
//   xfp   f32 [6][8192][128]      25,165,824 B
//   coefh/l u16 [128][64][128]  2x2,097,152 B  (latb aliases coefh, lw2T
//                               aliases coefl; pw1T aliases coefh at the end)
//   fwdFh/l u16 [4608][128] ; invFh/l u16 [128][4608] ; skwh/l u16 [4][64][64]
#define B_     128
#define T_     4096
#define TP_    4506
#define TPAD_  4608
#define KSPLIT 6
#define NL_    4

typedef __attribute__((ext_vector_type(8))) short bf16x8;
typedef __attribute__((ext_vector_type(4))) float f32x4;
typedef unsigned short u16;

__device__ __forceinline__ float silu_f(float x){
  return x / (1.0f + expf(-x));
}
__device__ __forceinline__ float silu_fast(float x){
  return __fdividef(x, 1.0f + __expf(-x));
}
__device__ __forceinline__ float gelu_f(float x){
  float u = x + 0.044715f*x*x*x;
  return 0.5f*x*(1.0f + tanhf(0.7978845608028654f*u));
}
__device__ __forceinline__ u16 bf16_rne(float f){
  unsigned u = __float_as_uint(f);
  unsigned r = u + 0x7FFFu + ((u >> 16) & 1u);
  return (u16)(r >> 16);
}
__device__ __forceinline__ void bf16_split(float f, u16& h, u16& l){
  h = bf16_rne(f);
  float fh = __uint_as_float(((unsigned)h) << 16);
  l = bf16_rne(f - fh);
}
__device__ __forceinline__ void silu_split(float v, u16& h, u16& l){
  float s = v / (1.0f + __expf(-v));
  bf16_split(s, h, l);
}
__device__ __forceinline__ f32x4 mfma16(bf16x8 a, bf16x8 b, f32x4 c){
  return __builtin_amdgcn_mfma_f32_16x16x32_bf16(a, b, c, 0, 0, 0);
}

// ---------------------------------------------------------------- tables
__global__ __launch_bounds__(256) void k_tables(u16* __restrict__ fwdFh,
    u16* __restrict__ fwdFl, u16* __restrict__ invFh, u16* __restrict__ invFl){
  int idx = blockIdx.x*256 + threadIdx.x;
  if(idx >= TPAD_*64) return;
  int t = idx >> 6, m = idx & 63;
  float c = 0.f, s = 0.f;
  if(t < TP_){
    int r = (int)(((long long)m * (long long)t) % TP_);
    double ang = 6.283185307179586476925287 * (double)r / (double)TP_;
    c = (float)cos(ang);
    s = -(float)sin(ang);
  }
  u16 ch, cl, sh, sl;
  bf16_split(c, ch, cl);
  bf16_split(s, sh, sl);
  fwdFh[t*128 + m] = ch;      fwdFl[t*128 + m] = cl;
  fwdFh[t*128 + 64 + m] = sh; fwdFl[t*128 + 64 + m] = sl;
  invFh[(long)m*TPAD_ + t] = ch;      invFl[(long)m*TPAD_ + t] = cl;
  invFh[(long)(64+m)*TPAD_ + t] = sh; invFl[(long)(64+m)*TPAD_ + t] = sl;
}

// skw + lw2^T -> bf16 hi/lo
__global__ __launch_bounds__(256) void k_prep(const float* __restrict__ skw,
    u16* __restrict__ skwh, u16* __restrict__ skwl,
    const float* __restrict__ lw2, u16* __restrict__ lw2Th,
    u16* __restrict__ lw2Tl){
  int i = blockIdx.x*256 + threadIdx.x;
  if(i < NL_*64*64){
    u16 h, l; bf16_split(skw[i], h, l);
    skwh[i] = h; skwl[i] = l;
  } else if(i < NL_*64*64 + 64*128){
    int j = i - NL_*64*64;
    int w = j >> 7, d = j & 127;
    u16 h, l; bf16_split(lw2[d*64 + w], h, l);
    lw2Th[j] = h; lw2Tl[j] = l;
  }
}

// pw1^T -> bf16 hi/lo (after last layer; coef region dead)
__global__ __launch_bounds__(256) void k_prep2(const float* __restrict__ pw1,
    u16* __restrict__ pw1Th, u16* __restrict__ pw1Tl){
  int i = blockIdx.x*256 + threadIdx.x;
  if(i >= 64*128) return;
  int d = i >> 6, w = i & 63;
  u16 h, l; bf16_split(pw1[w*128 + d], h, l);
  pw1Th[i] = h; pw1Tl[i] = l;
}

// ---------------------------------------------------------------- embed
__global__ __launch_bounds__(128) void k_embed(
    const float* __restrict__ pp,
    const float* __restrict__ ew1, const float* __restrict__ eb1,
    const float* __restrict__ ew2, const float* __restrict__ eb2,
    const float* __restrict__ ew3, const float* __restrict__ eb3,
    const float* __restrict__ lw1, const float* __restrict__ lb1,
    float* __restrict__ latb)
{
  int b = blockIdx.x, tid = threadIdx.x;
  __shared__ float p[64], h1[128], h2[128], e[32];
  if(tid < 64) p[tid] = pp[b*64 + tid];
  __syncthreads();
  {
    float z = eb1[tid];
    for(int j=0;j<64;j++) z += p[j]*ew1[j*128 + tid];
    h1[tid] = gelu_f(z);
  }
  __syncthreads();
  {
    float z = eb2[tid];
    for(int j=0;j<128;j++) z += h1[j]*ew2[j*128 + tid];
    h2[tid] = gelu_f(z);
  }
  __syncthreads();
  if(tid < 32){
    float z = eb3[tid];
    for(int j=0;j<128;j++) z += h2[j]*ew3[j*32 + tid];
    e[tid] = tanhf(z);
  }
  __syncthreads();
  {
    float v = lb1[tid];
    for(int c=0;c<32;c++) v += e[c]*lw1[(4+c)*128 + tid];
    latb[b*128 + tid] = v;
  }
}

// ---------------------------------------------------------------- lift (MFMA, R4 exact)
__global__ __launch_bounds__(256) void k_lift(
    const float* __restrict__ vterm, const float* __restrict__ latb,
    const float* __restrict__ lw1,  const u16* __restrict__ lw2Th,
    const u16* __restrict__ lw2Tl, const float* __restrict__ lb2,
    u16* __restrict__ hx, u16* __restrict__ lx)
{
  int tt = blockIdx.x, b = blockIdx.y, tid = threadIdx.x;
  int t0 = tt*128;
  if(t0 >= T_){
    int r = tid >> 2, t00 = (tid & 3)*32;
    bf16x8 z8 = (bf16x8){0,0,0,0,0,0,0,0};
    long base = ((long)b*64 + r)*TPAD_ + t0 + t00;
    #pragma unroll
    for(int q=0;q<4;q++){
      *(bf16x8*)(hx + base + q*8) = z8;
      *(bf16x8*)(lx + base + q*8) = z8;
    }
    return;
  }
  __shared__ u16 zz[32768];
  u16* zh = zz;
  u16* zl = zz + 16384;
  __shared__ float vt[512], lw1c[512], latbs[128];
  if(tid < 128){
    int c = tid >> 5, tc = (tid & 31)*4;
    *(float4*)(vt + c*128 + tc) =
      *(const float4*)(vterm + ((long)b*4 + c)*T_ + t0 + tc);
  } else {
    int i = (tid - 128)*4;
    *(float4*)(lw1c + i) = *(const float4*)(lw1 + i);
  }
  if(tid < 32)
    *(float4*)(latbs + tid*4) = *(const float4*)(latb + b*128 + tid*4);
  __syncthreads();
  {
    int t = tid >> 1, dh = (tid & 1)*64;
    float v0 = vt[t], v1 = vt[128+t], v2 = vt[256+t], v3 = vt[384+t];
    int swz = (t & 7) << 4;
    #pragma unroll
    for(int q=0;q<16;q++){
      int d0 = dh + q*4;
      float4 w0 = *(const float4*)(lw1c + d0);
      float4 w1 = *(const float4*)(lw1c + 128 + d0);
      float4 w2 = *(const float4*)(lw1c + 256 + d0);
      float4 w3 = *(const float4*)(lw1c + 384 + d0);
      float4 lb = *(const float4*)(latbs + d0);
      u16 h0,h1,h2,h3,l0,l1,l2,l3;
      silu_split(lb.x + w0.x*v0 + w1.x*v1 + w2.x*v2 + w3.x*v3, h0, l0);
      silu_split(lb.y + w0.y*v0 + w1.y*v1 + w2.y*v2 + w3.y*v3, h1, l1);
      silu_split(lb.z + w0.z*v0 + w1.z*v1 + w2.z*v2 + w3.z*v3, h2, l2);
      silu_split(lb.w + w0.w*v0 + w1.w*v1 + w2.w*v2 + w3.w*v3, h3, l3);
      int byt = (t*256 + d0*2) ^ swz;
      uint2 hv = make_uint2((unsigned)h0 | ((unsigned)h1<<16),
                            (unsigned)h2 | ((unsigned)h3<<16));
      uint2 lv = make_uint2((unsigned)l0 | ((unsigned)l1<<16),
                            (unsigned)l2 | ((unsigned)l3<<16));
      *(uint2*)((char*)zh + byt) = hv;
      *(uint2*)((char*)zl + byt) = lv;
    }
  }
  __syncthreads();
  int lane = tid & 63, w = tid >> 6;
  int l15 = lane & 15, lhi = lane >> 4;
  int n0 = w*32;
  f32x4 acc[4][2];
  #pragma unroll
  for(int mi=0;mi<4;mi++){
    #pragma unroll
    for(int ni=0;ni<2;ni++) acc[mi][ni] = (f32x4){0.f,0.f,0.f,0.f};
  }
  #pragma unroll
  for(int ks=0; ks<4; ++ks){
    bf16x8 Ah[4], Al[4], Bh[2], Bl[2];
    #pragma unroll
    for(int mi=0;mi<4;mi++){
      int o = mi*16 + l15;
      long off = (long)o*128 + ks*32 + lhi*8;
      Ah[mi] = *(const bf16x8*)(lw2Th + off);
      Al[mi] = *(const bf16x8*)(lw2Tl + off);
    }
    #pragma unroll
    for(int ni=0;ni<2;ni++){
      int t = n0 + ni*16 + l15;
      int byt = (t*256 + (ks*32 + lhi*8)*2) ^ ((t & 7) << 4);
      Bh[ni] = *(bf16x8*)((char*)zh + byt);
      Bl[ni] = *(bf16x8*)((char*)zl + byt);
    }
    #pragma unroll
    for(int mi=0;mi<4;mi++){
      #pragma unroll
      for(int ni=0;ni<2;ni++){
        acc[mi][ni] = mfma16(Ah[mi], Bh[ni], acc[mi][ni]);
        acc[mi][ni] = mfma16(Al[mi], Bh[ni], acc[mi][ni]);
        acc[mi][ni] = mfma16(Ah[mi], Bl[ni], acc[mi][ni]);
      }
    }
  }
  __syncthreads();
  float* fo = (float*)zz;
  #pragma unroll
  for(int mi=0;mi<4;mi++){
    #pragma unroll
    for(int ni=0;ni<2;ni++){
      #pragma unroll
      for(int r=0;r<4;r++){
        int o = mi*16 + lhi*4 + r;
        int tl = n0 + ni*16 + l15;
        fo[o*128 + (tl ^ ((o&7)<<2))] = acc[mi][ni][r];
      }
    }
  }
  __syncthreads();
  #pragma unroll
  for(int q=0;q<8;q++){
    int idx = q*256 + tid;
    int o = idx >> 5, tb = idx & 31;
    float4 rd = *(const float4*)(fo + o*128 + ((tb*4) ^ ((o&7)<<2)));
    float bias = lb2[o];
    u16 h0,h1,h2,h3,l0,l1,l2,l3;
    silu_split(rd.x + bias, h0, l0);
    silu_split(rd.y + bias, h1, l1);
    silu_split(rd.z + bias, h2, l2);
    silu_split(rd.w + bias, h3, l3);
    long base = ((long)b*64 + o)*TPAD_ + t0 + tb*4;
    *(uint2*)(hx + base) = make_uint2((unsigned)h0 | ((unsigned)h1<<16),
                                      (unsigned)h2 | ((unsigned)h3<<16));
    *(uint2*)(lx + base) = make_uint2((unsigned)l0 | ((unsigned)l1<<16),
                                      (unsigned)l2 | ((unsigned)l3<<16));
  }
}

// ---------------------------------------------------------------- forward DFT (LDS-staged, XCD-swizzled)
// xfp[s][(b*64+c)][j] = sum_{t in split s} h[b][c][t] * F_inv[j][t]
__global__ __launch_bounds__(256) void k_dftS(
    const u16* __restrict__ hx, const u16* __restrict__ lx,
    const u16* __restrict__ invFh, const u16* __restrict__ invFl,
    float* __restrict__ xfp)
{
  int wg  = blockIdx.x;
  int wgp = (wg & 7)*96 + (wg >> 3);   // bijective: same-XCD blocks share s
  int s = wgp >> 7, b = wgp & 127;
  int tid = threadIdx.x;
  int lane = tid & 63, w = tid >> 6;
  int l15 = lane & 15, lhi = lane >> 4;
  int n0 = w*32;
  __shared__ u16 ah[8192], al[8192];   // [c][128t] swizzled, 32 KB
  f32x4 acc[4][2];
  #pragma unroll
  for(int mi=0;mi<4;mi++){
    #pragma unroll
    for(int ni=0;ni<2;ni++) acc[mi][ni] = (f32x4){0.f,0.f,0.f,0.f};
  }
  int cst = tid >> 2, t4 = (tid & 3)*32;
  int swz = (cst & 7) << 4;
  for(int ch=0; ch<6; ++ch){
    long k0 = (long)s*768 + ch*128;
    if(ch) __syncthreads();
    { // stage tile: pure copy (activations already silu'd + split)
      const u16* ph = hx + ((long)b*64 + cst)*TPAD_ + k0 + t4;
      const u16* pl = lx + ((long)b*64 + cst)*TPAD_ + k0 + t4;
      #pragma unroll
      for(int q=0;q<4;q++){
        bf16x8 hv = *(const bf16x8*)(ph + q*8);
        bf16x8 lv = *(const bf16x8*)(pl + q*8);
        int byt = (cst*256 + (t4 + q*8)*2) ^ swz;
        *(bf16x8*)((char*)ah + byt) = hv;
        *(bf16x8*)((char*)al + byt) = lv;
      }
    }
    __syncthreads();
    #pragma unroll
    for(int ks=0; ks<4; ++ks){
      bf16x8 Ah[4], Al[4], Bh[2], Bl[2];
      #pragma unroll
      for(int mi=0;mi<4;mi++){
        int c = mi*16 + l15;
        int byt = (c*256 + (ks*32 + lhi*8)*2) ^ ((c & 7) << 4);
        Ah[mi] = *(bf16x8*)((char*)ah + byt);
        Al[mi] = *(bf16x8*)((char*)al + byt);
      }
      #pragma unroll
      for(int ni=0;ni<2;ni++){
        int j = n0 + ni*16 + l15;
        long off = (long)j*TPAD_ + k0 + ks*32 + lhi*8;
        Bh[ni] = *(const bf16x8*)(invFh + off);
        Bl[ni] = *(const bf16x8*)(invFl + off);
      }
      #pragma unroll
      for(int mi=0;mi<4;mi++){
        #pragma unroll
        for(int ni=0;ni<2;ni++){
          acc[mi][ni] = mfma16(Ah[mi], Bh[ni], acc[mi][ni]);
          acc[mi][ni] = mfma16(Al[mi], Bh[ni], acc[mi][ni]);
          acc[mi][ni] = mfma16(Ah[mi], Bl[ni], acc[mi][ni]);
        }
      }
    }
  }
  #pragma unroll
  for(int mi=0;mi<4;mi++){
    #pragma unroll
    for(int ni=0;ni<2;ni++){
      #pragma unroll
      for(int r=0;r<4;r++){
        int row = mi*16 + lhi*4 + r;
        int j = n0 + ni*16 + l15;
        xfp[((long)s*8192 + b*64 + row)*128 + j] = acc[mi][ni][r];
      }
    }
  }
}

// ---------------------------------------------------------------- spectral mix (6 splits)
__global__ __launch_bounds__(512) void k_spectral(
    const float* __restrict__ xfp, const float* __restrict__ wr_,
    const float* __restrict__ wi_, u16* __restrict__ coefh,
    u16* __restrict__ coefl, int l)
{
  int b = blockIdx.x, mh = blockIdx.y, tid = threadIdx.x;
  const float* wr = wr_ + (long)l*262144;
  const float* wi = wi_ + (long)l*262144;
  __shared__ float xr[64*36], xi[64*36];
  {
    int c = tid >> 3, mm0 = (tid & 7)*4;
    long base = ((long)(b*64 + c))*128 + mh*32 + mm0;
    float4 sr = make_float4(0.f,0.f,0.f,0.f), si = sr;
    #pragma unroll
    for(int s2=0;s2<KSPLIT;s2++){
      const float* p = xfp + (long)s2*1048576 + base;
      float4 a = *(const float4*)(p);
      float4 d = *(const float4*)(p + 64);
      sr.x += a.x; sr.y += a.y; sr.z += a.z; sr.w += a.w;
      si.x += d.x; si.y += d.y; si.z += d.z; si.w += d.w;
    }
    *(float4*)(xr + c*36 + mm0) = sr;
    *(float4*)(xi + c*36 + mm0) = si;
  }
  __syncthreads();
  int tx = tid & 15, ty = tid >> 4;
  float ar[2][2] = {{0.f,0.f},{0.f,0.f}};
  float ai[2][2] = {{0.f,0.f},{0.f,0.f}};
  #pragma unroll 2
  for(int c=0;c<64;c++){
    float x0r = xr[c*36 + 2*tx], x1r = xr[c*36 + 2*tx + 1];
    float x0i = xi[c*36 + 2*tx], x1i = xi[c*36 + 2*tx + 1];
    #pragma unroll
    for(int oi=0;oi<2;oi++){
      int o = 2*ty + oi;
      long wofs = ((long)(c*64 + o))*64 + mh*32 + 2*tx;
      float2 wrv = *(const float2*)(wr + wofs);
      float2 wiv = *(const float2*)(wi + wofs);
      ar[oi][0] += x0r*wrv.x - x0i*wiv.x;
      ai[oi][0] += x0r*wiv.x + x0i*wrv.x;
      ar[oi][1] += x1r*wrv.y - x1i*wiv.y;
      ai[oi][1] += x1r*wiv.y + x1i*wrv.y;
    }
  }
  #pragma unroll
  for(int j=0;j<2;j++){
    int m = mh*32 + 2*tx + j;
    float sc = (m==0) ? (1.0f/(float)TP_) : (2.0f/(float)TP_);
    #pragma unroll
    for(int oi=0;oi<2;oi++){
      int o = 2*ty + oi;
      long base = ((long)b*64 + o)*128;
      u16 h, l2;
      bf16_split(sc*ar[oi][j], h, l2);
      coefh[base + m] = h; coefl[base + m] = l2;
      bf16_split(sc*ai[oi][j], h, l2);
      coefh[base + 64 + m] = h; coefl[base + 64 + m] = l2;
    }
  }
}

// ---------------------------------------------------------------- inverse DFT + skip
// staging remapped for coalesced reads; swizzle extended to ((t&7)^(t>>4))<<4
// (write <=2-way banks, read bank-set identical to R4-measured-zero pattern)
__global__ __launch_bounds__(256) void k_idft(
    u16* __restrict__ hx, u16* __restrict__ lx,
    const u16* __restrict__ coefh, const u16* __restrict__ coefl,
    const u16* __restrict__ fwdFh, const u16* __restrict__ fwdFl,
    const u16* __restrict__ skwh, const u16* __restrict__ skwl,
    const float* __restrict__ sb_, int lay, int last)
{
  int tt = blockIdx.x, b = blockIdx.y, tid = threadIdx.x;
  int t0 = tt*128;
  int lane = tid & 63, w = tid >> 6;
  int l15 = lane & 15, lhi = lane >> 4;
  int n0 = w*32;
  __shared__ u16 sh_[16384];           // hh[128t][64c], hl ; fo f32 aliases
  u16* hh = sh_;
  u16* hl = sh_ + 8192;
  { // stage h transposed [t][c]; coalesced: 8 lanes sweep 256B per row-pair
    int cp = tid >> 3, seg = tid & 7;
    int c0 = cp*2;
    const u16* ph0 = hx + ((long)b*64 + c0)*TPAD_ + t0 + seg*16;
    const u16* ph1 = ph0 + TPAD_;
    const u16* pl0 = lx + ((long)b*64 + c0)*TPAD_ + t0 + seg*16;
    const u16* pl1 = pl0 + TPAD_;
    bf16x8 h0a = *(const bf16x8*)(ph0),     h0b = *(const bf16x8*)(ph0 + 8);
    bf16x8 h1a = *(const bf16x8*)(ph1),     h1b = *(const bf16x8*)(ph1 + 8);
    bf16x8 l0a = *(const bf16x8*)(pl0),     l0b = *(const bf16x8*)(pl0 + 8);
    bf16x8 l1a = *(const bf16x8*)(pl1),     l1b = *(const bf16x8*)(pl1 + 8);
    #pragma unroll
    for(int i=0;i<8;i++){
      int t = seg*16 + i;
      int byt = (t*128 + c0*2) ^ ((((t & 7) ^ seg) & 7) << 4);
      *(unsigned*)((char*)hh + byt) =
        (unsigned)(u16)h0a[i] | ((unsigned)(u16)h1a[i] << 16);
      *(unsigned*)((char*)hl + byt) =
        (unsigned)(u16)l0a[i] | ((unsigned)(u16)l1a[i] << 16);
    }
    #pragma unroll
    for(int i=0;i<8;i++){
      int t = seg*16 + 8 + i;
      int byt = (t*128 + c0*2) ^ ((((t & 7) ^ seg) & 7) << 4);
      *(unsigned*)((char*)hh + byt) =
        (unsigned)(u16)h0b[i] | ((unsigned)(u16)h1b[i] << 16);
      *(unsigned*)((char*)hl + byt) =
        (unsigned)(u16)l0b[i] | ((unsigned)(u16)l1b[i] << 16);
    }
  }
  f32x4 acc[4][2];
  #pragma unroll
  for(int mi=0;mi<4;mi++){
    #pragma unroll
    for(int ni=0;ni<2;ni++) acc[mi][ni] = (f32x4){0.f,0.f,0.f,0.f};
  }
  // phase 1: spectral, K=128 (coef x trig), global frags
  #pragma unroll
  for(int ks=0; ks<4; ++ks){
    bf16x8 Ah[4], Al[4], Bh[2], Bl[2];
    #pragma unroll
    for(int mi=0;mi<4;mi++){
      int o = mi*16 + l15;
      long off = ((long)(b*64 + o))*128 + ks*32 + lhi*8;
      Ah[mi] = *(const bf16x8*)(coefh + off);
      Al[mi] = *(const bf16x8*)(coefl + off);
    }
    #pragma unroll
    for(int ni=0;ni<2;ni++){
      int t = t0 + n0 + ni*16 + l15;
      long off = (long)t*128 + ks*32 + lhi*8;
      Bh[ni] = *(const bf16x8*)(fwdFh + off);
      Bl[ni] = *(const bf16x8*)(fwdFl + off);
    }
    #pragma unroll
    for(int mi=0;mi<4;mi++){
      #pragma unroll
      for(int ni=0;ni<2;ni++){
        acc[mi][ni] = mfma16(Ah[mi], Bh[ni], acc[mi][ni]);
        acc[mi][ni] = mfma16(Al[mi], Bh[ni], acc[mi][ni]);
        acc[mi][ni] = mfma16(Ah[mi], Bl[ni], acc[mi][ni]);
      }
    }
  }
  __syncthreads();
  // phase 2: skip GEMM, K=64 (skw x h), B from LDS
  #pragma unroll
  for(int ks=0; ks<2; ++ks){
    bf16x8 Ah[4], Al[4], Bh[2], Bl[2];
    #pragma unroll
    for(int mi=0;mi<4;mi++){
      int o = mi*16 + l15;
      long off = (long)lay*4096 + o*64 + ks*32 + lhi*8;
      Ah[mi] = *(const bf16x8*)(skwh + off);
      Al[mi] = *(const bf16x8*)(skwl + off);
    }
    #pragma unroll
    for(int ni=0;ni<2;ni++){
      int t = n0 + ni*16 + l15;
      int byt = (t*128 + (ks*32 + lhi*8)*2) ^ ((((t & 7) ^ (t >> 4)) & 7) << 4);
      Bh[ni] = *(bf16x8*)((char*)hh + byt);
      Bl[ni] = *(bf16x8*)((char*)hl + byt);
    }
    #pragma unroll
    for(int mi=0;mi<4;mi++){
      #pragma unroll
      for(int ni=0;ni<2;ni++){
        acc[mi][ni] = mfma16(Ah[mi], Bh[ni], acc[mi][ni]);
        acc[mi][ni] = mfma16(Al[mi], Bh[ni], acc[mi][ni]);
        acc[mi][ni] = mfma16(Ah[mi], Bl[ni], acc[mi][ni]);
      }
    }
  }
  __syncthreads();
  float* fo = (float*)sh_;   // [64 o][128 t], xor-swizzled
  #pragma unroll
  for(int mi=0;mi<4;mi++){
    #pragma unroll
    for(int ni=0;ni<2;ni++){
      #pragma unroll
      for(int r=0;r<4;r++){
        int o = mi*16 + lhi*4 + r;
        int tl = n0 + ni*16 + l15;
        fo[o*128 + (tl ^ ((o&7)<<2))] = acc[mi][ni][r];
      }
    }
  }
  __syncthreads();
  #pragma unroll
  for(int q=0;q<8;q++){
    int idx = q*256 + tid;
    int o = idx >> 5, tb = idx & 31;
    float4 rd = *(const float4*)(fo + o*128 + ((tb*4) ^ ((o&7)<<2)));
    float bias = sb_[lay*64 + o];
    float v[4] = {rd.x + bias, rd.y + bias, rd.z + bias, rd.w + bias};
    int tg = t0 + tb*4;
    #pragma unroll
    for(int j=0;j<4;j++){
      if(tg + j >= TP_) v[j] = 0.f;
      else if(!last)    v[j] = silu_fast(v[j]);
    }
    u16 h0,h1,h2,h3,l0,l1,l2,l3;
    bf16_split(v[0], h0, l0);
    bf16_split(v[1], h1, l1);
    bf16_split(v[2], h2, l2);
    bf16_split(v[3], h3, l3);
    long base = ((long)b*64 + o)*TPAD_ + t0 + tb*4;
    *(uint2*)(hx + base) = make_uint2((unsigned)h0 | ((unsigned)h1<<16),
                                      (unsigned)h2 | ((unsigned)h3<<16));
    *(uint2*)(lx + base) = make_uint2((unsigned)l0 | ((unsigned)l1<<16),
                                      (unsigned)l2 | ((unsigned)l3<<16));
  }
}

// ---------------------------------------------------------------- projection (MFMA, fast-silu epilogue)
__global__ __launch_bounds__(256) void k_proj(
    const u16* __restrict__ hx, const u16* __restrict__ lx,
    const u16* __restrict__ pw1Th, const u16* __restrict__ pw1Tl,
    const float* __restrict__ pb1, const float* __restrict__ pw2,
    const float* __restrict__ pb2, float* __restrict__ out)
{
  int tt = blockIdx.x, b = blockIdx.y, tid = threadIdx.x;
  int t0 = tt*128;
  int lane = tid & 63, w = tid >> 6;
  int l15 = lane & 15, lhi = lane >> 4;
  __shared__ u16 sh_[16384];           // x tile transposed [128t][64c] h/l
  u16* hh = sh_;
  u16* hl = sh_ + 8192;
  {
    int c0 = (tid & 31)*2, tg = tid >> 5;
    const u16* ph0 = hx + ((long)b*64 + c0)*TPAD_ + t0 + tg*16;
    const u16* ph1 = ph0 + TPAD_;
    const u16* pl0 = lx + ((long)b*64 + c0)*TPAD_ + t0 + tg*16;
    const u16* pl1 = pl0 + TPAD_;
    bf16x8 h0a = *(const bf16x8*)(ph0),     h0b = *(const bf16x8*)(ph0 + 8);
    bf16x8 h1a = *(const bf16x8*)(ph1),     h1b = *(const bf16x8*)(ph1 + 8);
    bf16x8 l0a = *(const bf16x8*)(pl0),     l0b = *(const bf16x8*)(pl0 + 8);
    bf16x8 l1a = *(const bf16x8*)(pl1),     l1b = *(const bf16x8*)(pl1 + 8);
    #pragma unroll
    for(int i=0;i<8;i++){
      int t = tg*16 + i;
      int byt = (t*128 + c0*2) ^ ((t & 7) << 4);
      *(unsigned*)((char*)hh + byt) =
        (unsigned)(u16)h0a[i] | ((unsigned)(u16)h1a[i] << 16);
      *(unsigned*)((char*)hl + byt) =
        (unsigned)(u16)l0a[i] | ((unsigned)(u16)l1a[i] << 16);
    }
    #pragma unroll
    for(int i=0;i<8;i++){
      int t = tg*16 + 8 + i;
      int byt = (t*128 + c0*2) ^ ((t & 7) << 4);
      *(unsigned*)((char*)hh + byt) =
        (unsigned)(u16)h0b[i] | ((unsigned)(u16)h1b[i] << 16);
      *(unsigned*)((char*)hl + byt) =
        (unsigned)(u16)l0b[i] | ((unsigned)(u16)l1b[i] << 16);
    }
  }
  __syncthreads();
  f32x4 acc[2][8];
  #pragma unroll
  for(int mi=0;mi<2;mi++){
    #pragma unroll
    for(int ni=0;ni<8;ni++) acc[mi][ni] = (f32x4){0.f,0.f,0.f,0.f};
  }
  #pragma unroll
  for(int ks=0; ks<2; ++ks){
    bf16x8 Ah[2], Al[2], Bh[8], Bl[8];
    #pragma unroll
    for(int mi=0;mi<2;mi++){
      int t = w*32 + mi*16 + l15;
      int byt = (t*128 + (ks*32 + lhi*8)*2) ^ ((t & 7) << 4);
      Ah[mi] = *(bf16x8*)((char*)hh + byt);
      Al[mi] = *(bf16x8*)((char*)hl + byt);
    }
    #pragma unroll
    for(int ni=0;ni<8;ni++){
      long off = (long)(ni*16 + l15)*64 + ks*32 + lhi*8;
      Bh[ni] = *(const bf16x8*)(pw1Th + off);
      Bl[ni] = *(const bf16x8*)(pw1Tl + off);
    }
    #pragma unroll
    for(int mi=0;mi<2;mi++){
      #pragma unroll
      for(int ni=0;ni<8;ni++){
        acc[mi][ni] = mfma16(Ah[mi], Bh[ni], acc[mi][ni]);
        acc[mi][ni] = mfma16(Al[mi], Bh[ni], acc[mi][ni]);
        acc[mi][ni] = mfma16(Ah[mi], Bl[ni], acc[mi][ni]);
      }
    }
  }
  #pragma unroll
  for(int mi=0;mi<2;mi++){
    #pragma unroll
    for(int r=0;r<4;r++){
      int t = w*32 + mi*16 + lhi*4 + r;
      float s = 0.f;
      #pragma unroll
      for(int ni=0;ni<8;ni++){
        int d = ni*16 + l15;
        s += pw2[d] * silu_fast(acc[mi][ni][r] + pb1[d]);
      }
      s += __shfl_xor(s, 1);
      s += __shfl_xor(s, 2);
      s += __shfl_xor(s, 4);
      s += __shfl_xor(s, 8);
      if(l15 == 0) out[(long)b*T_ + t0 + t] = s + pb2[0];
    }
  }
}

// ---------------------------------------------------------------- launch
extern "C" void kernel_launch(void* const* d_in, const int* in_sizes, int n_in,
                              void* d_out, int out_size, void* d_ws, size_t ws_size,
                              hipStream_t stream)
{
  const float* vterm = (const float*)d_in[0];
  const float* pp    = (const float*)d_in[1];
  const float* ew1   = (const float*)d_in[2];
  const float* eb1   = (const float*)d_in[3];
  const float* ew2   = (const float*)d_in[4];
  const float* eb2   = (const float*)d_in[5];
  const float* ew3   = (const float*)d_in[6];
  const float* eb3   = (const float*)d_in[7];
  const float* lw1   = (const float*)d_in[8];
  const float* lb1   = (const float*)d_in[9];
  const float* lw2   = (const float*)d_in[10];
  const float* lb2   = (const float*)d_in[11];
  const float* swr   = (const float*)d_in[12];
  const float* swi   = (const float*)d_in[13];
  const float* skw   = (const float*)d_in[14];
  const float* skb   = (const float*)d_in[15];
  const float* pw1   = (const float*)d_in[16];
  const float* pb1   = (const float*)d_in[17];
  const float* pw2   = (const float*)d_in[18];
  const float* pb2   = (const float*)d_in[19];
  float* out = (float*)d_out;

  u16* hx     = (u16*)d_ws;
  u16* lxp    = hx + 37748736;
  float* xfp  = (float*)(lxp + 37748736);
  u16* coefh  = (u16*)(xfp + 6291456);
  u16* coefl  = coefh + 1048576;
  u16* fwdFh  = coefl + 1048576;
  u16* fwdFl  = fwdFh + 589824;
  u16* invFh  = fwdFl + 589824;
  u16* invFl  = invFh + 589824;
  u16* skwh   = invFl + 589824;
  u16* skwl   = skwh + 16384;
  float* latb = (float*)coefh;   // dead before spectral writes coef
  u16* lw2Th  = coefl;           // dead before spectral writes coef
  u16* lw2Tl  = coefl + 8192;
  u16* pw1Th  = coefh;           // written by k_prep2 after coef is dead
  u16* pw1Tl  = coefh + 8192;

  k_tables<<<(TPAD_*64 + 255)/256, 256, 0, stream>>>(fwdFh, fwdFl, invFh, invFl);
  k_prep<<<(NL_*64*64 + 64*128 + 255)/256, 256, 0, stream>>>(
      skw, skwh, skwl, lw2, lw2Th, lw2Tl);
  k_embed<<<B_, 128, 0, stream>>>(pp, ew1, eb1, ew2, eb2, ew3, eb3, lw1, lb1, latb);
  k_lift<<<dim3(TPAD_/128, B_), 256, 0, stream>>>(
      vterm, latb, lw1, lw2Th, lw2Tl, lb2, hx, lxp);
  for(int l=0;l<NL_;l++){
    k_dftS<<<B_*KSPLIT, 256, 0, stream>>>(hx, lxp, invFh, invFl, xfp);
    k_spectral<<<dim3(B_, 2), 512, 0, stream>>>(xfp, swr, swi, coefh, coefl, l);
    k_idft<<<dim3(TPAD_/128, B_), 256, 0, stream>>>(
        hx, lxp, coefh, coefl, fwdFh, fwdFl, skwh, skwl, skb, l,
        (l==NL_-1) ? 1 : 0);
  }
  k_prep2<<<32, 256, 0, stream>>>(pw1, pw1Th, pw1Tl);
  k_proj<<<dim3(T_/128, B_), 256, 0, stream>>>(
      hx, lxp, pw1Th, pw1Tl, pb1, pw2, pb2, out);
}